// Round 21
// baseline (1072.252 us; speedup 1.0000x reference)
//
#include <hip/hip_runtime.h>
#include <hip/hip_bf16.h>
#include <math.h>
#include <type_traits>

typedef __hip_bfloat16 bf16;
typedef __attribute__((ext_vector_type(8))) short bf16x8;
typedef __attribute__((ext_vector_type(4))) float f32x4;

__device__ __forceinline__ float b2f(bf16 x){ return __bfloat162float(x); }
__device__ __forceinline__ short f2s(float f){
  bf16 h = __float2bfloat16(f);
  short s; __builtin_memcpy(&s, &h, 2); return s;
}
__device__ __forceinline__ float u2f(unsigned short u){ union { unsigned int i; float f; } z; z.i = ((unsigned int)u) << 16; return z.f; }
__device__ __forceinline__ bf16x8 cvt8(float4 a, float4 b){
  return (bf16x8){f2s(a.x),f2s(a.y),f2s(a.z),f2s(a.w), f2s(b.x),f2s(b.y),f2s(b.z),f2s(b.w)};
}

// ==================== one-shot weight conversion fp32 -> bf16 (12 tensors, 11,534,336 elems) ====================
struct WSrc { const float* p[12]; };
__global__ __launch_bounds__(256) void k_cvtw(WSrc srcs, bf16* __restrict__ dst){
  const unsigned off[13] = {0u,262144u,524288u,786432u,2359296u,2883584u,4456448u,4980736u,
                            6553600u,7077888u,9175040u,11272192u,11534336u};
  size_t base = ((size_t)blockIdx.x*256 + threadIdx.x)*8;   // 8-elem chunks never span segments
  int seg = 0;
  while (seg < 11 && base >= off[seg+1]) seg++;
  const float* s = srcs.p[seg] + (base - off[seg]);
  float4 a = *(const float4*)s;
  float4 b = *(const float4*)(s + 4);
  *(bf16x8*)&dst[base] = cvt8(a, b);
}

// ==================== MFMA GEMM 128xBN: static dbuf, ADD-rotation chunk swizzle, 1 barrier/step ====================
// physical_chunk(c,row) = (c + (row>>3)) & 3 : the 4 aliasing row-groups (Δrow=8 at 80B stride)
// land logical chunk c in 4 distinct banks-slots -> writes & reads <=2-way (free).
template<typename AT, typename WT, typename CT, int ACT, int BN, int RES>
__global__ __launch_bounds__(256, BN == 64 ? 2 : 1)
void k_gemm_mfma(const AT* __restrict__ A, const WT* __restrict__ W,
                 const float* __restrict__ bias, CT* C,
                 const float* Rres, int rows, int Kd, int Nc)
{
  __shared__ short As[2][128][40];   // 80 B row stride; dbuf
  __shared__ short Bs[2][BN][40];
  constexpr int NI = BN / 32;
  int rb = blockIdx.x * 128, nb = blockIdx.y * BN;
  int tid = threadIdx.x;
  int l = tid & 63, w = tid >> 6;
  int wr = (w >> 1) * 64, wc = (w & 1) * (BN/2);
  int lr = l & 15, lk = l >> 4;
  f32x4 acc[4][NI];
  #pragma unroll
  for (int i = 0; i < 4; i++)
    #pragma unroll
    for (int j = 0; j < NI; j++)
      acc[i][j] = (f32x4){0.f, 0.f, 0.f, 0.f};
  int sr = tid >> 1;
  int s4 = (sr >> 3) & 3;
  int p2 = (tid & 1) * 2;                     // logical chunks p2, p2+1
  int psc1 = ((p2 + s4) & 3) * 8;             // physical (shorts)
  int psc2 = ((p2 + 1 + s4) & 3) * 8;
  // read: logical chunk lk at row (wr + mi*16 + lr): phys = (lk + (lr>>3) + 2*mi) & 3
  int rcE = ((lk + (lr >> 3)) & 3) * 8;       // mi even
  int rcO = ((lk + (lr >> 3) + 2) & 3) * 8;   // mi odd
  bool doB = (BN == 128) || (tid < 128);
  bool doA = (rb + sr) < rows;

  float4 fa[4], fb[4];
  bf16x8 ba[2], wb[2];
  #pragma unroll
  for (int i = 0; i < 4; i++){ fa[i] = (float4){0,0,0,0}; fb[i] = (float4){0,0,0,0}; }
  ba[0] = ba[1] = wb[0] = wb[1] = (bf16x8){0,0,0,0,0,0,0,0};

  int sc = (tid & 1) * 16;   // global-source column (unswizzled)
  auto LOADS = [&](int k0){
    if constexpr (std::is_same<AT, float>::value){
      if (doA){
        const float4* p = (const float4*)(A + (size_t)(rb + sr)*Kd + k0 + sc);
        fa[0] = p[0]; fa[1] = p[1]; fa[2] = p[2]; fa[3] = p[3];
      }
    } else {
      if (doA){
        const bf16x8* p = (const bf16x8*)((const unsigned short*)A + (size_t)(rb + sr)*Kd + k0 + sc);
        ba[0] = p[0]; ba[1] = p[1];
      }
    }
    if (doB){
      if constexpr (std::is_same<WT, float>::value){
        const float4* p = (const float4*)(W + (size_t)(nb + sr)*Kd + k0 + sc);
        fb[0] = p[0]; fb[1] = p[1]; fb[2] = p[2]; fb[3] = p[3];
      } else {
        const bf16x8* p = (const bf16x8*)((const unsigned short*)W + (size_t)(nb + sr)*Kd + k0 + sc);
        wb[0] = p[0]; wb[1] = p[1];
      }
    }
  };
  auto STOREK = [&](int buf){
    if constexpr (std::is_same<AT, float>::value){
      *(bf16x8*)&As[buf][sr][psc1] = cvt8(fa[0], fa[1]);
      *(bf16x8*)&As[buf][sr][psc2] = cvt8(fa[2], fa[3]);
    } else {
      *(bf16x8*)&As[buf][sr][psc1] = ba[0];
      *(bf16x8*)&As[buf][sr][psc2] = ba[1];
    }
    if (doB){
      if constexpr (std::is_same<WT, float>::value){
        *(bf16x8*)&Bs[buf][sr][psc1] = cvt8(fb[0], fb[1]);
        *(bf16x8*)&Bs[buf][sr][psc2] = cvt8(fb[2], fb[3]);
      } else {
        *(bf16x8*)&Bs[buf][sr][psc1] = wb[0];
        *(bf16x8*)&Bs[buf][sr][psc2] = wb[1];
      }
    }
  };
  auto COMPUTE = [&](int buf){
    bf16x8 af[4], bf_[NI];
    #pragma unroll
    for (int mi = 0; mi < 4; mi++)
      af[mi]  = *(const bf16x8*)&As[buf][wr + mi*16 + lr][(mi & 1) ? rcO : rcE];
    #pragma unroll
    for (int ni = 0; ni < NI; ni++)
      bf_[ni] = *(const bf16x8*)&Bs[buf][wc + ni*16 + lr][(ni & 1) ? rcO : rcE];
    #pragma unroll
    for (int mi = 0; mi < 4; mi++)
      #pragma unroll
      for (int ni = 0; ni < NI; ni++)
        acc[mi][ni] = __builtin_amdgcn_mfma_f32_16x16x32_bf16(af[mi], bf_[ni], acc[mi][ni], 0, 0, 0);
  };

  int nst = Kd >> 5;                    // 16 or 64 — always even
  LOADS(0);
  STOREK(0);
  LOADS(32);
  __syncthreads();
  for (int s = 0; s < nst; s += 2){
    COMPUTE(0);
    STOREK(1);                          // regs hold tile s+1
    if (s + 2 < nst) LOADS((s + 2) * 32);
    __syncthreads();
    COMPUTE(1);
    if (s + 2 < nst){
      STOREK(0);                        // regs hold tile s+2
      if (s + 3 < nst) LOADS((s + 3) * 32);
      __syncthreads();
    }
  }

  #pragma unroll
  for (int mi = 0; mi < 4; mi++){
    #pragma unroll
    for (int ni = 0; ni < NI; ni++){
      int col = nb + wc + ni*16 + lr;
      float bs = bias[col];
      #pragma unroll
      for (int r = 0; r < 4; r++){
        int row = rb + wr + mi*16 + lk*4 + r;
        if (row < rows){
          float v = acc[mi][ni][r] + bs;
          if (RES) v += Rres[(size_t)row*Nc + col];
          if (ACT == 1) v = 0.5f*v*(1.0f + erff(v*0.70710678118654752f));
          if constexpr (std::is_same<CT, float>::value) C[(size_t)row*Nc + col] = v;
          else C[(size_t)row*Nc + col] = __float2bfloat16(v);
        }
      }
    }
  }
}

// ==================== MFMA GEMM 64x64: static-index LDS dbuf (R20-proven mapping) ====================
template<typename AT, typename WT, typename CT, int ACT, int RES>
__global__ __launch_bounds__(256, 4)
void k_gemm64(const AT* __restrict__ A, const WT* __restrict__ W,
              const float* __restrict__ bias, CT* C,
              const float* Rres, int rows, int Kd, int Nc)
{
  __shared__ short As[2][64][40];
  __shared__ short Bs[2][64][40];
  int rb = blockIdx.x * 64, nb = blockIdx.y * 64;
  int tid = threadIdx.x;
  int l = tid & 63, w = tid >> 6;
  int wr = (w >> 1) * 32, wc = (w & 1) * 32;
  int lr = l & 15, lk = l >> 4;
  f32x4 acc[2][2];
  #pragma unroll
  for (int i = 0; i < 2; i++)
    #pragma unroll
    for (int j = 0; j < 2; j++)
      acc[i][j] = (f32x4){0.f, 0.f, 0.f, 0.f};
  int sr = tid >> 2;            // row 0..63, 4 threads/row
  int sc = (tid & 3) * 8;       // global-source column (unswizzled)
  int psc = (((tid & 3) ^ (((sr >> 3) & 1) << 1))) * 8;
  int rchunk = (lk ^ (((lr >> 3) & 1) << 1)) * 8;
  bool doA = (rb + sr) < rows;

  float4 fa[2], fw[2];
  bf16x8 ba, wb;
  fa[0] = fa[1] = fw[0] = fw[1] = (float4){0,0,0,0};
  ba = wb = (bf16x8){0,0,0,0,0,0,0,0};

  auto LOADS = [&](int k0){
    if constexpr (std::is_same<AT, float>::value){
      if (doA){
        const float4* p = (const float4*)(A + (size_t)(rb + sr)*Kd + k0 + sc);
        fa[0] = p[0]; fa[1] = p[1];
      }
    } else {
      if (doA) ba = *(const bf16x8*)((const unsigned short*)A + (size_t)(rb + sr)*Kd + k0 + sc);
    }
    if constexpr (std::is_same<WT, float>::value){
      const float4* p = (const float4*)(W + (size_t)(nb + sr)*Kd + k0 + sc);
      fw[0] = p[0]; fw[1] = p[1];
    } else {
      wb = *(const bf16x8*)((const unsigned short*)W + (size_t)(nb + sr)*Kd + k0 + sc);
    }
  };
  auto STOREK = [&](int buf){
    if constexpr (std::is_same<AT, float>::value) *(bf16x8*)&As[buf][sr][psc] = cvt8(fa[0], fa[1]);
    else                                          *(bf16x8*)&As[buf][sr][psc] = ba;
    if constexpr (std::is_same<WT, float>::value) *(bf16x8*)&Bs[buf][sr][psc] = cvt8(fw[0], fw[1]);
    else                                          *(bf16x8*)&Bs[buf][sr][psc] = wb;
  };
  auto COMPUTE = [&](int buf){
    bf16x8 af[2], bf_[2];
    #pragma unroll
    for (int mi = 0; mi < 2; mi++) af[mi]  = *(const bf16x8*)&As[buf][wr + mi*16 + lr][rchunk];
    #pragma unroll
    for (int ni = 0; ni < 2; ni++) bf_[ni] = *(const bf16x8*)&Bs[buf][wc + ni*16 + lr][rchunk];
    #pragma unroll
    for (int mi = 0; mi < 2; mi++)
      #pragma unroll
      for (int ni = 0; ni < 2; ni++)
        acc[mi][ni] = __builtin_amdgcn_mfma_f32_16x16x32_bf16(af[mi], bf_[ni], acc[mi][ni], 0, 0, 0);
  };

  int nst = Kd >> 5;                    // even
  LOADS(0);
  STOREK(0);
  LOADS(32);
  __syncthreads();
  for (int s = 0; s < nst; s += 2){
    COMPUTE(0);
    STOREK(1);
    if (s + 2 < nst) LOADS((s + 2) * 32);
    __syncthreads();
    COMPUTE(1);
    if (s + 2 < nst){
      STOREK(0);
      if (s + 3 < nst) LOADS((s + 3) * 32);
      __syncthreads();
    }
  }

  #pragma unroll
  for (int mi = 0; mi < 2; mi++){
    #pragma unroll
    for (int ni = 0; ni < 2; ni++){
      int col = nb + wc + ni*16 + lr;
      float bs = bias[col];
      #pragma unroll
      for (int r = 0; r < 4; r++){
        int row = rb + wr + mi*16 + lk*4 + r;
        if (row < rows){
          float v = acc[mi][ni][r] + bs;
          if (RES) v += Rres[(size_t)row*Nc + col];
          if (ACT == 1) v = 0.5f*v*(1.0f + erff(v*0.70710678118654752f));
          if constexpr (std::is_same<CT, float>::value) C[(size_t)row*Nc + col] = v;
          else C[(size_t)row*Nc + col] = __float2bfloat16(v);
        }
      }
    }
  }
}

// ==================== row LayerNorm (D=512), optional residual + relu. NO restrict (may run in place). ====================
template<typename XT, typename OT>
__global__ __launch_bounds__(256) void k_ln(const XT* X, const float* R,
                                            const float* g, const float* bt,
                                            OT* out, int relu)
{
  __shared__ float red[4];
  int row = blockIdx.x, t = threadIdx.x;
  size_t base = (size_t)row * 512;
  float x0, x1;
  if constexpr (std::is_same<XT, float>::value){ x0 = X[base + t]; x1 = X[base + t + 256]; }
  else { x0 = b2f(X[base + t]); x1 = b2f(X[base + t + 256]); }
  if (R){ x0 += R[base + t]; x1 += R[base + t + 256]; }
  float v = x0 + x1;
  #pragma unroll
  for (int o = 32; o > 0; o >>= 1) v += __shfl_xor(v, o);
  if ((t & 63) == 0) red[t >> 6] = v;
  __syncthreads();
  float mean = (red[0]+red[1]+red[2]+red[3]) * (1.0f/512.0f);
  float d0 = x0 - mean, d1 = x1 - mean;
  v = d0*d0 + d1*d1;
  #pragma unroll
  for (int o = 32; o > 0; o >>= 1) v += __shfl_xor(v, o);
  __syncthreads();
  if ((t & 63) == 0) red[t >> 6] = v;
  __syncthreads();
  float var = (red[0]+red[1]+red[2]+red[3]) * (1.0f/512.0f);
  float is = 1.0f / sqrtf(var + 1e-5f);
  float y0 = d0*is*g[t] + bt[t];
  float y1 = d1*is*g[t+256] + bt[t+256];
  if (relu){ y0 = fmaxf(y0, 0.0f); y1 = fmaxf(y1, 0.0f); }
  if constexpr (std::is_same<OT, float>::value){ out[base + t] = y0; out[base + t + 256] = y1; }
  else { out[base + t] = __float2bfloat16(y0); out[base + t + 256] = __float2bfloat16(y1); }
}

// ==================== bev transpose [64, 512, 256] f32 -> [16384, 512] bf16 ====================
__global__ void k_bev_tok(const float* __restrict__ bev, bf16* __restrict__ out){
  __shared__ float tile[32][33];
  int b = blockIdx.z;
  int d0 = blockIdx.x * 32;
  int p0 = blockIdx.y * 32;
  int tx = threadIdx.x, ty = threadIdx.y;
  #pragma unroll
  for (int i = 0; i < 4; i++){
    int d = d0 + ty + i*8;
    tile[ty + i*8][tx] = bev[((size_t)b*512 + d)*256 + p0 + tx];
  }
  __syncthreads();
  #pragma unroll
  for (int i = 0; i < 4; i++){
    int p = p0 + ty + i*8;
    out[((size_t)b*256 + p)*512 + d0 + tx] = __float2bfloat16(tile[tx][ty + i*8]);
  }
}

// ==================== top-K agents + invalid mask ====================
__global__ void k_topk(const float* __restrict__ labels, const float* __restrict__ states,
                       int* __restrict__ idxo, int* __restrict__ invo)
{
  __shared__ float dist[32];
  __shared__ int valid[32];
  int b = blockIdx.x, t = threadIdx.x;
  if (t < 32){
    float lab = labels[b*32 + t];
    float sg = 1.0f / (1.0f + expf(-lab));
    int va = sg > 0.05f;
    float x = states[((size_t)b*32 + t)*8 + 0];
    float y = states[((size_t)b*32 + t)*8 + 1];
    float d = sqrtf(__fadd_rn(__fmul_rn(x,x), __fmul_rn(y,y)));
    dist[t] = va ? d : INFINITY;
    valid[t] = va;
  }
  __syncthreads();
  if (t == 0){
    unsigned used = 0;
    int inv8[8]; int allinv = 1;
    for (int kk = 0; kk < 8; kk++){
      float best = INFINITY; int bi = -1;
      for (int i = 0; i < 32; i++){
        if (used & (1u << i)) continue;
        if (bi < 0 || dist[i] < best){ best = dist[i]; bi = i; }
      }
      used |= 1u << bi;
      idxo[b*8 + kk] = bi;
      inv8[kk] = !valid[bi];
      allinv &= inv8[kk];
    }
    for (int kk = 0; kk < 8; kk++) invo[b*8 + kk] = allinv ? 0 : inv8[kk];
  }
}

// ==================== gather agents f32 -> bf16 [512,512] ====================
__global__ void k_gather(const float* __restrict__ aq, const int* __restrict__ idx, bf16* __restrict__ out)
{
  int rk = blockIdx.x; int b = rk >> 3;
  int src = idx[rk] & 31;
  int t = threadIdx.x;
  size_t sbase = ((size_t)(b*32 + src))*512;
  out[(size_t)rk*512 + t]       = __float2bfloat16(aq[sbase + t]);
  out[(size_t)rk*512 + t + 256] = __float2bfloat16(aq[sbase + t + 256]);
}

// ==================== agent_kv f32 enc -> bf16 [4096,512] ====================
__global__ void k_agentkv(const float* __restrict__ enc, const float* __restrict__ step_e,
                          const float* __restrict__ role_e, bf16* __restrict__ out)
{
  int row = blockIdx.x;
  int t8 = row & 7; int bk = row >> 3;
  int tx = threadIdx.x;
  #pragma unroll
  for (int j = 0; j < 2; j++){
    int d = tx + j*256;
    out[(size_t)row*512 + d] = __float2bfloat16((enc[(size_t)bk*512 + d] + step_e[t8*512 + d]) + role_e[512 + d]);
  }
}

// ==================== sequential codebook NN scan -> tokens [B,T] ====================
__global__ __launch_bounds__(64) void k_cbscan(const float* __restrict__ gt, const float* __restrict__ cb,
                                               int* __restrict__ toks)
{
  __shared__ float cbx[512], cby[512];
  int b = blockIdx.x;
  int l = threadIdx.x;
  #pragma unroll
  for (int i = 0; i < 8; i++){
    int v = l + i*64;
    cbx[v] = cb[v*2 + 0];
    cby[v] = cb[v*2 + 1];
  }
  __syncthreads();
  float ax = 0.0f, ay = 0.0f;
  for (int t = 0; t < 8; t++){
    float px = gt[(b*8 + t)*3 + 0];
    float py = gt[(b*8 + t)*3 + 1];
    float bestv = INFINITY; int besti = 0;
    #pragma unroll
    for (int i = 0; i < 8; i++){
      int v = l*8 + i;
      float dx = __fsub_rn(__fadd_rn(ax, cbx[v]), px);
      float dy = __fsub_rn(__fadd_rn(ay, cby[v]), py);
      float d = __fadd_rn(__fmul_rn(dx,dx), __fmul_rn(dy,dy));
      if (d < bestv || (d == bestv && v < besti)){ bestv = d; besti = v; }
    }
    #pragma unroll
    for (int o = 32; o > 0; o >>= 1){
      float ov = __shfl_xor(bestv, o);
      int oi = __shfl_xor(besti, o);
      if (ov < bestv || (ov == bestv && oi < besti)){ bestv = ov; besti = oi; }
    }
    ax = __fadd_rn(ax, cbx[besti]);
    ay = __fadd_rn(ay, cby[besti]);
    if (l == 0) toks[b*8 + t] = besti;
  }
}

// ==================== teacher-forced embedding -> egoq f32 ====================
__global__ void k_embed(const int* __restrict__ toks, const float* __restrict__ ebase,
                        const float* __restrict__ tok_emb, const float* __restrict__ step_e,
                        const float* __restrict__ mode_e, const float* __restrict__ role_e,
                        const float* __restrict__ bos_e, float* __restrict__ out)
{
  int row = blockIdx.x;
  int t = row & 7; int bm = row >> 3; int m = bm % 20; int b = bm / 20;
  int tok = (t == 0) ? 0 : (toks[b*8 + t - 1] & 511);
  int tx = threadIdx.x;
  #pragma unroll
  for (int j = 0; j < 2; j++){
    int d = tx + j*256;
    float base = (t == 0) ? (bos_e[d] + ebase[(size_t)b*512 + d])
                          : tok_emb[(size_t)tok*512 + d];
    out[(size_t)row*512 + d] = ((base + step_e[t*512 + d]) + role_e[d]) + mode_e[m*512 + d];
  }
}

// ==================== temporal causal attention (QKV bf16 [rows,1536] -> O bf16) ====================
__global__ __launch_bounds__(64) void k_tattn(const bf16* __restrict__ QKV, bf16* __restrict__ O)
{
  __shared__ float q[8][65], k[8][65], v[8][65], w[8][9];
  int h = blockIdx.x & 7; int bm = blockIdx.x >> 3;
  int l = threadIdx.x;
  for (int t = 0; t < 8; t++){
    size_t base = ((size_t)(bm*8 + t))*1536 + h*64 + l;
    q[t][l] = b2f(QKV[base]);
    k[t][l] = b2f(QKV[base + 512]);
    v[t][l] = b2f(QKV[base + 1024]);
  }
  __syncthreads();
  int tq = l >> 3, tk = l & 7;
  float s = -INFINITY;
  if (tk <= tq){
    float acc = 0.0f;
    #pragma unroll
    for (int e = 0; e < 64; e++) acc += q[tq][e]*k[tk][e];
    s = acc * 0.125f;
  }
  float mx = s;
  #pragma unroll
  for (int o = 1; o < 8; o <<= 1) mx = fmaxf(mx, __shfl_xor(mx, o));
  float ex = (tk <= tq) ? expf(s - mx) : 0.0f;
  float sm = ex;
  #pragma unroll
  for (int o = 1; o < 8; o <<= 1) sm += __shfl_xor(sm, o);
  w[tq][tk] = ex / sm;
  __syncthreads();
  #pragma unroll
  for (int t2 = 0; t2 < 8; t2++){
    float acc = 0.0f;
    #pragma unroll
    for (int tk2 = 0; tk2 < 8; tk2++) acc += w[t2][tk2]*v[tk2][l];
    O[((size_t)(bm*8 + t2))*512 + h*64 + l] = __float2bfloat16(acc);
  }
}

// ==================== ego-to-agent cross-attention; KV interleaved [4096,1024] (K|V) ====================
__global__ __launch_bounds__(64) void k_eattn(const bf16* __restrict__ Q, const bf16* __restrict__ KV,
                                              const int* __restrict__ inv,
                                              bf16* __restrict__ O, int row0)
{
  int blk = blockIdx.x;
  int h = blockIdx.y;
  int grow = row0 + blk;
  int t = grow & 7;
  int b = grow / 160;
  int l = threadIdx.x;
  size_t qoff = (size_t)blk*512 + h*64 + l;
  float q = b2f(Q[qoff]);
  float s[8];
  #pragma unroll
  for (int k = 0; k < 8; k++){
    float p = q * b2f(KV[((size_t)((b*8 + k)*8 + t))*1024 + h*64 + l]);
    #pragma unroll
    for (int o = 32; o > 0; o >>= 1) p += __shfl_xor(p, o);
    s[k] = p * 0.125f;
  }
  float mx = -INFINITY;
  #pragma unroll
  for (int k = 0; k < 8; k++){
    if (inv[b*8 + k]) s[k] = -INFINITY;
    mx = fmaxf(mx, s[k]);
  }
  float sum = 0.0f, w[8];
  #pragma unroll
  for (int k = 0; k < 8; k++){ w[k] = expf(s[k] - mx); sum += w[k]; }
  float rs = 1.0f / sum;
  float acc = 0.0f;
  #pragma unroll
  for (int k = 0; k < 8; k++)
    acc += (w[k]*rs) * b2f(KV[((size_t)((b*8 + k)*8 + t))*1024 + 512 + h*64 + l]);
  O[qoff] = __float2bfloat16(acc);
}

// ==================== BEV cross-attention v5 (MFMA flash-style); bl spans grid.x ====================
__global__ __launch_bounds__(256, 2) void k_vattn(const bf16* __restrict__ Q, const bf16* __restrict__ KV,
                                                  bf16* __restrict__ O)
{
  __shared__ unsigned short Ks[256][72];   // P [32][264] aliases this after scores
  __shared__ unsigned short Vt[64][264];   // V transposed [e][key]
  __shared__ float red[2][2][16];
  unsigned short (*P_lds)[264] = (unsigned short (*)[264])&Ks[0][0];

  int bl = blockIdx.x, h = blockIdx.y, qz = blockIdx.z;
  int tid = threadIdx.x;
  const unsigned short* KVr = (const unsigned short*)KV;

  {
    const uint4* ksrc = (const uint4*)&KVr[((size_t)(bl*256 + tid))*1024 + h*64];
    const uint4* vsrc = (const uint4*)&KVr[((size_t)(bl*256 + tid))*1024 + 512 + h*64];
    #pragma unroll
    for (int i = 0; i < 8; i++){
      uint4 kx = ksrc[i];
      *(uint4*)&Ks[tid][i*8] = kx;
    }
    #pragma unroll
    for (int i = 0; i < 8; i++){
      uint4 vx = vsrc[i];
      unsigned short vs[8];
      __builtin_memcpy(vs, &vx, 16);
      #pragma unroll
      for (int j = 0; j < 8; j++) Vt[i*8 + j][tid] = vs[j];
    }
  }
  __syncthreads();

  int w = tid >> 6, l = tid & 63, lr = l & 15, lk = l >> 4;
  int mt = w >> 1, ch = w & 1;

  int qrow = bl*160 + qz*32 + mt*16 + lr;
  const unsigned short* Qr = (const unsigned short*)Q;
  bf16x8 qf0 = *(const bf16x8*)&Qr[(size_t)qrow*512 + h*64 + lk*8];
  bf16x8 qf1 = *(const bf16x8*)&Qr[(size_t)qrow*512 + h*64 + 32 + lk*8];

  f32x4 sacc[8];
  #pragma unroll
  for (int nt = 0; nt < 8; nt++) sacc[nt] = (f32x4){0.f,0.f,0.f,0.f};
  #pragma unroll
  for (int nt = 0; nt < 8; nt++){
    int key0 = ch*128 + nt*16 + lr;
    bf16x8 kf0 = *(const bf16x8*)&Ks[key0][lk*8];
    bf16x8 kf1 = *(const bf16x8*)&Ks[key0][32 + lk*8];
    sacc[nt] = __builtin_amdgcn_mfma_f32_16x16x32_bf16(qf0, kf0, sacc[nt], 0, 0, 0);
    sacc[nt] = __builtin_amdgcn_mfma_f32_16x16x32_bf16(qf1, kf1, sacc[nt], 0, 0, 0);
  }

  float rmax[4] = {-INFINITY, -INFINITY, -INFINITY, -INFINITY};
  #pragma unroll
  for (int nt = 0; nt < 8; nt++)
    #pragma unroll
    for (int r = 0; r < 4; r++){
      float v = sacc[nt][r] * 0.125f;
      sacc[nt][r] = v;
      rmax[r] = fmaxf(rmax[r], v);
    }
  #pragma unroll
  for (int r = 0; r < 4; r++){
    #pragma unroll
    for (int o = 1; o < 16; o <<= 1) rmax[r] = fmaxf(rmax[r], __shfl_xor(rmax[r], o));
  }
  if (lr == 0){
    #pragma unroll
    for (int r = 0; r < 4; r++) red[mt][ch][lk*4 + r] = rmax[r];
  }
  __syncthreads();
  float m4[4];
  #pragma unroll
  for (int r = 0; r < 4; r++) m4[r] = fmaxf(red[mt][0][lk*4 + r], red[mt][1][lk*4 + r]);
  float rsum[4] = {0.f, 0.f, 0.f, 0.f};
  #pragma unroll
  for (int nt = 0; nt < 8; nt++){
    #pragma unroll
    for (int r = 0; r < 4; r++){
      float e = expf(sacc[nt][r] - m4[r]);
      rsum[r] += e;
      P_lds[mt*16 + lk*4 + r][ch*128 + nt*16 + lr] = (unsigned short)f2s(e);
    }
  }
  #pragma unroll
  for (int r = 0; r < 4; r++){
    #pragma unroll
    for (int o = 1; o < 16; o <<= 1) rsum[r] += __shfl_xor(rsum[r], o);
  }
  __syncthreads();
  if (lr == 0){
    #pragma unroll
    for (int r = 0; r < 4; r++) red[mt][ch][lk*4 + r] = rsum[r];
  }
  __syncthreads();
  float rcp4[4];
  #pragma unroll
  for (int r = 0; r < 4; r++) rcp4[r] = 1.0f / (red[mt][0][lk*4 + r] + red[mt][1][lk*4 + r]);

  f32x4 oacc0 = (f32x4){0.f,0.f,0.f,0.f};
  f32x4 oacc1 = (f32x4){0.f,0.f,0.f,0.f};
  #pragma unroll
  for (int kk = 0; kk < 8; kk++){
    bf16x8 pf  = *(const bf16x8*)&P_lds[mt*16 + lr][kk*32 + lk*8];
    bf16x8 vf0 = *(const bf16x8*)&Vt[ch*32 + lr][kk*32 + lk*8];
    bf16x8 vf1 = *(const bf16x8*)&Vt[ch*32 + 16 + lr][kk*32 + lk*8];
    oacc0 = __builtin_amdgcn_mfma_f32_16x16x32_bf16(pf, vf0, oacc0, 0, 0, 0);
    oacc1 = __builtin_amdgcn_mfma_f32_16x16x32_bf16(pf, vf1, oacc1, 0, 0, 0);
  }

  {
    size_t obase = ((size_t)(bl*160 + qz*32 + mt*16 + lk*4))*512 + h*64 + ch*32 + lr;
    #pragma unroll
    for (int r = 0; r < 4; r++){
      O[obase + (size_t)r*512]      = __float2bfloat16(oacc0[r] * rcp4[r]);
      O[obase + (size_t)r*512 + 16] = __float2bfloat16(oacc1[r] * rcp4[r]);
    }
  }
}

// ==================== launchers ====================
template<typename AT, typename CT, int ACT, int BN, int RES>
static inline void launch_gemm(bool wbf, const AT* A, const float* Wf, const bf16* Wb,
                               const float* bias, CT* C, const float* Rr,
                               int rows, int Kd, int Nc, hipStream_t st){
  dim3 g((rows + 127)/128, Nc/BN);
  if (wbf) k_gemm_mfma<AT,bf16,CT,ACT,BN,RES><<<g,256,0,st>>>(A, Wb, bias, C, Rr, rows, Kd, Nc);
  else     k_gemm_mfma<AT,float,CT,ACT,BN,RES><<<g,256,0,st>>>(A, Wf, bias, C, Rr, rows, Kd, Nc);
}
template<typename AT, typename CT, int ACT, int RES>
static inline void launch_gemm64(bool wbf, const AT* A, const float* Wf, const bf16* Wb,
                                 const float* bias, CT* C, const float* Rr,
                                 int rows, int Kd, int Nc, hipStream_t st){
  dim3 g((rows + 63)/64, Nc/64);
  if (wbf) k_gemm64<AT,bf16,CT,ACT,RES><<<g,256,0,st>>>(A, Wb, bias, C, Rr, rows, Kd, Nc);
  else     k_gemm64<AT,float,CT,ACT,RES><<<g,256,0,st>>>(A, Wf, bias, C, Rr, rows, Kd, Nc);
}

extern "C" void kernel_launch(void* const* d_in, const int* in_sizes, int n_in,
                              void* d_out, int out_size, void* d_ws, size_t ws_size,
                              hipStream_t stream)
{
  (void)in_sizes; (void)n_in; (void)out_size;
  const float* ego_query    = (const float*)d_in[0];
  const float* agents_query = (const float*)d_in[1];
  const float* bev_feature  = (const float*)d_in[2];
  const float* agent_states = (const float*)d_in[3];
  const float* agent_labels = (const float*)d_in[4];
  const float* gt_traj      = (const float*)d_in[5];
  const float* codebook     = (const float*)d_in[6];
  const float* ego_ctx_w    = (const float*)d_in[7];
  const float* ego_ctx_b    = (const float*)d_in[8];
  const float* ego_ctx_g    = (const float*)d_in[9];
  const float* ego_ctx_beta = (const float*)d_in[10];
  const float* bevproj_w    = (const float*)d_in[11];
  const float* bevproj_b    = (const float*)d_in[12];
  const float* bevproj_g    = (const float*)d_in[13];
  const float* bevproj_beta = (const float*)d_in[14];
  const float* agent_w      = (const float*)d_in[15];
  const float* agent_b      = (const float*)d_in[16];
  const float* agent_g      = (const float*)d_in[17];
  const float* agent_beta   = (const float*)d_in[18];
  const float* tok_emb      = (const float*)d_in[19];
  const float* step_e       = (const float*)d_in[20];
  const float* mode_e       = (const float*)d_in[21];
  const float* role_e       = (const float*)d_in[22];
  const float* bos_e        = (const float*)d_in[23];
  const float* t_qkv_w      = (const float*)d_in[24];
  const float* t_qkv_b      = (const float*)d_in[25];
  const float* t_out_w      = (const float*)d_in[26];
  const float* t_out_b      = (const float*)d_in[27];
  const float* t_g          = (const float*)d_in[28];
  const float* t_beta       = (const float*)d_in[29];
  const float* e_qkv_w      = (const float*)d_in[30];
  const float* e_qkv_b      = (const float*)d_in[31];
  const float* e_out_w      = (const float*)d_in[32];
  const float* e_out_b      = (const float*)d_in[33];
  const float* e_g          = (const float*)d_in[34];
  const float* e_beta       = (const float*)d_in[35];
  const float* v_qkv_w      = (const float*)d_in[36];
  const float* v_qkv_b      = (const float*)d_in[37];
  const float* v_out_w      = (const float*)d_in[38];
  const float* v_out_b      = (const float*)d_in[39];
  const float* v_g          = (const float*)d_in[40];
  const float* v_beta       = (const float*)d_in[41];
  const float* ffn_w1       = (const float*)d_in[42];
  const float* ffn_b1       = (const float*)d_in[43];
  const float* ffn_w2       = (const float*)d_in[44];
  const float* ffn_b2       = (const float*)d_in[45];
  const float* ffn_g        = (const float*)d_in[46];
  const float* ffn_beta     = (const float*)d_in[47];
  const float* head_w       = (const float*)d_in[48];
  const float* head_b       = (const float*)d_in[49];

  // ---- workspace tiers: small 46.3 / big 67.3 / big2 100.8 / big3 123.9 MB (bf16 weights) ----
  const size_t NEEDED       = 46274560;
  const size_t NEEDED_BIG   = 67248128;
  const size_t NEEDED_BIG2  = 100800512;
  const size_t NEEDED_BIG3  = 123869184;
  if (ws_size < NEEDED) return;
  bool big  = ws_size >= NEEDED_BIG;
  bool big2 = ws_size >= NEEDED_BIG2;
  bool big3 = ws_size >= NEEDED_BIG3;
  int RC  = big ? 10240 : 5120;
  int NCH = big ? 1 : 2;

  char* WB = (char*)d_ws;
  bf16*  bevtok = (bf16*)(WB + 0);          // [16384,512] bf16 persistent
  bf16*  akv    = (bf16*)(WB + 16777216);   // [4096,512] bf16 persistent
  float* ebase  = (float*)(WB + 20971520);  // [64,512] f32
  char*  ARENA  = WB + 21102592;
  bf16*  KVb    = (bf16*)(WB + 37879808);   // [4096,1024] bf16
  bf16*  KVbig  = (bf16*)(WB + 67239936);   // [16384,1024] bf16 (big2+)
  bf16*  WCV    = (bf16*)(WB + 100800512);  // [11,534,336] bf16 converted weights (big3)
  size_t tk0    = big2 ? 100794368 : (big ? 67239936 : 46268416);
  int*   toks   = (int*)(WB + tk0);
  int*   idxb   = (int*)(WB + tk0 + 2048);
  int*   invb   = (int*)(WB + tk0 + 4096);
  size_t oe_off = big ? 31457280 : 5242880;

  float* egoq = (float*)d_out;   // [10240,512] f32 residual stream lives in d_out

  // converted-weight element offsets
  bf16* c_bevproj = WCV + 0;
  bf16* c_ego     = WCV + 262144;
  bf16* c_agent   = WCV + 524288;
  bf16* c_tqkv    = WCV + 786432;
  bf16* c_tout    = WCV + 2359296;
  bf16* c_eqkv    = WCV + 2883584;
  bf16* c_eout    = WCV + 4456448;
  bf16* c_vqkv    = WCV + 4980736;
  bf16* c_vout    = WCV + 6553600;
  bf16* c_ffn1    = WCV + 7077888;
  bf16* c_ffn2    = WCV + 9175040;
  bf16* c_head    = WCV + 11272192;

  if (big3){
    WSrc src;
    src.p[0] = bevproj_w; src.p[1] = ego_ctx_w; src.p[2] = agent_w;  src.p[3] = t_qkv_w;
    src.p[4] = t_out_w;   src.p[5] = e_qkv_w;   src.p[6] = e_out_w;  src.p[7] = v_qkv_w;
    src.p[8] = v_out_w;   src.p[9] = ffn_w1;    src.p[10] = ffn_w2;  src.p[11] = head_w;
    k_cvtw<<<5632, 256, 0, stream>>>(src, WCV);
  }

  #define GEMM(AT,CT,ACT,BN,RES, Ap, Wf, Wb, Bp,Cp,Rp, R,K,N) \
    launch_gemm<AT,CT,ACT,BN,RES>(big3, Ap, Wf, Wb, Bp, Cp, Rp, R, K, N, stream)
  #define GEMM64(AT,CT,ACT,RES, Ap, Wf, Wb, Bp,Cp,Rp, R,K,N) \
    launch_gemm64<AT,CT,ACT,RES>(big3, Ap, Wf, Wb, Bp, Cp, Rp, R, K, N, stream)

  // --- BEV tokens ONCE ---
  {
    bf16* raw = (bf16*)ARENA;   // [16384,512]
    k_bev_tok<<<dim3(16, 8, 64), dim3(32, 8), 0, stream>>>(bev_feature, raw);
    GEMM64(bf16,bf16,0,0, raw, bevproj_w, c_bevproj, bevproj_b, bevtok, nullptr, 16384, 512, 512);
    k_ln<bf16,bf16><<<16384, 256, 0, stream>>>(bevtok, nullptr, bevproj_g, bevproj_beta, bevtok, 1);
  }

  // --- ego base ---
  GEMM64(float,float,0,0, ego_query, ego_ctx_w, c_ego, ego_ctx_b, (float*)ARENA, nullptr, 64, 512, 512);
  k_ln<float,float><<<64, 256, 0, stream>>>((float*)ARENA, nullptr, ego_ctx_g, ego_ctx_beta, ebase, 1);

  // --- agents ---
  k_topk<<<64, 64, 0, stream>>>(agent_labels, agent_states, idxb, invb);
  {
    bf16*  gat = (bf16*)ARENA;                   // [512,512] bf16
    float* enc = (float*)(ARENA + 524288);       // [512,512] f32
    k_gather<<<512, 256, 0, stream>>>(agents_query, idxb, gat);
    GEMM64(bf16,float,0,0, gat, agent_w, c_agent, agent_b, enc, nullptr, 512, 512, 512);
    k_ln<float,float><<<512, 256, 0, stream>>>(enc, nullptr, agent_g, agent_beta, enc, 1);
    k_agentkv<<<4096, 256, 0, stream>>>(enc, step_e, role_e, akv);
  }

  // --- tokens + embedding ---
  k_cbscan<<<64, 64, 0, stream>>>(gt_traj, codebook, toks);
  k_embed<<<10240, 256, 0, stream>>>(toks, ebase, tok_emb, step_e, mode_e, role_e, bos_e, egoq);

  for (int i = 0; i < 2; i++){
    // ---- temporal self-attention ----
    {
      bf16* QKV = (bf16*)ARENA;                 // [RC,1536]
      bf16* Ot  = big ? (bf16*)(ARENA + oe_off) : KVb;   // [RC,512]
      for (int c = 0; c < NCH; c++){
        float* eg = egoq + (size_t)c*RC*512;
        GEMM(float,bf16,0,128,0, eg, t_qkv_w + (size_t)i*786432, c_tqkv + (size_t)i*786432,
             t_qkv_b + i*1536, QKV, nullptr, RC, 512, 1536);
        k_tattn<<<RC, 64, 0, stream>>>(QKV, Ot);
        GEMM64(bf16,float,0,1, Ot, t_out_w + (size_t)i*262144, c_tout + (size_t)i*262144,
             t_out_b + i*512, eg, eg, RC, 512, 512);
      }
      k_ln<float,float><<<10240, 256, 0, stream>>>(egoq, nullptr, t_g + i*512, t_beta + i*512, egoq, 0);
    }
    // ---- ego-to-agent cross-attention ----
    {
      const float* eqw = e_qkv_w + (size_t)i*786432;
      bf16*        eqc = c_eqkv + (size_t)i*786432;
      const float* eqb = e_qkv_b + i*1536;
      bf16* Qe = (bf16*)ARENA;                  // [RC,512]
      bf16* Oe = (bf16*)(ARENA + oe_off);       // [RC,512]
      GEMM64(bf16,bf16,0,0, akv, eqw + 262144, eqc + 262144, eqb + 512, KVb, nullptr, 4096, 512, 1024);
      for (int c = 0; c < NCH; c++){
        float* eg = egoq + (size_t)c*RC*512;
        GEMM64(float,bf16,0,0, eg, eqw, eqc, eqb, Qe, nullptr, RC, 512, 512);
        k_eattn<<<dim3(RC, 8), 64, 0, stream>>>(Qe, KVb, invb, Oe, c*RC);
        GEMM64(bf16,float,0,1, Oe, e_out_w + (size_t)i*262144, c_eout + (size_t)i*262144,
             e_out_b + i*512, eg, eg, RC, 512, 512);
      }
      k_ln<float,float><<<10240, 256, 0, stream>>>(egoq, nullptr, e_g + i*512, e_beta + i*512, egoq, 0);
    }
    // ---- BEV cross-attention ----
    {
      const float* vqw = v_qkv_w + (size_t)i*786432;
      bf16*        vqc = c_vqkv + (size_t)i*786432;
      const float* vqb = v_qkv_b + i*1536;
      if (big2){
        bf16* Qv = (bf16*)ARENA;                  // [10240,512]
        bf16* Ov = (bf16*)(ARENA + 10485760);     // [10240,512]
        GEMM64(bf16,bf16,0,0, bevtok, vqw + 262144, vqc + 262144, vqb + 512, KVbig, nullptr, 16384, 512, 1024);
        GEMM64(float,bf16,0,0, egoq, vqw, vqc, vqb, Qv, nullptr, 10240, 512, 512);
        k_vattn<<<dim3(64, 8, 5), 256, 0, stream>>>(Qv, KVbig, Ov);
        GEMM64(bf16,float,0,1, Ov, v_out_w + (size_t)i*262144, c_vout + (size_t)i*262144,
             v_out_b + i*512, egoq, egoq, 10240, 512, 512);
      } else {
        bf16* Qv = (bf16*)ARENA;                  // [2560,512]
        bf16* Ov = (bf16*)(ARENA + 2621440);      // [2560,512]
        for (int gidx = 0; gidx < 4; gidx++){
          float* eg = egoq + (size_t)gidx*2560*512;
          GEMM64(bf16,bf16,0,0, bevtok + (size_t)gidx*4096*512, vqw + 262144, vqc + 262144,
               vqb + 512, KVb, nullptr, 4096, 512, 1024);
          GEMM64(float,bf16,0,0, eg, vqw, vqc, vqb, Qv, nullptr, 2560, 512, 512);
          k_vattn<<<dim3(16, 8, 5), 256, 0, stream>>>(Qv, KVb, Ov);
          GEMM64(bf16,float,0,1, Ov, v_out_w + (size_t)i*262144, c_vout + (size_t)i*262144,
               v_out_b + i*512, eg, eg, 2560, 512, 512);
        }
      }
      k_ln<float,float><<<10240, 256, 0, stream>>>(egoq, nullptr, v_g + i*512, v_beta + i*512, egoq, 0);
    }
    // ---- FFN ----
    {
      bf16* hid = (bf16*)ARENA;   // [RC,2048]
      for (int c = 0; c < NCH; c++){
        float* eg = egoq + (size_t)c*RC*512;
        GEMM(float,bf16,1,128,0, eg, ffn_w1 + (size_t)i*1048576, c_ffn1 + (size_t)i*1048576,
             ffn_b1 + i*2048, hid, nullptr, RC, 512, 2048);
        GEMM64(bf16,float,0,1, hid, ffn_w2 + (size_t)i*1048576, c_ffn2 + (size_t)i*1048576,
             ffn_b2 + i*512, eg, eg, RC, 2048, 512);
      }
      if (i == 0){
        k_ln<float,float><<<10240, 256, 0, stream>>>(egoq, nullptr, ffn_g, ffn_beta, egoq, 0);
      } else {
        k_ln<float,bf16><<<10240, 256, 0, stream>>>(egoq, nullptr, ffn_g + 512, ffn_beta + 512, (bf16*)ARENA, 0);
      }
    }
  }

  // --- head ---
  GEMM64(bf16,float,0,0, (bf16*)ARENA, head_w, c_head, head_b, (float*)d_out, nullptr, 10240, 512, 512);
  #undef GEMM
  #undef GEMM64
}

// Round 22
// 1004.619 us; speedup vs baseline: 1.0673x; 1.0673x over previous
//
#include <hip/hip_runtime.h>
#include <hip/hip_bf16.h>
#include <math.h>
#include <type_traits>

typedef __hip_bfloat16 bf16;
typedef __attribute__((ext_vector_type(8))) short bf16x8;
typedef __attribute__((ext_vector_type(4))) float f32x4;

__device__ __forceinline__ float b2f(bf16 x){ return __bfloat162float(x); }
__device__ __forceinline__ short f2s(float f){
  bf16 h = __float2bfloat16(f);
  short s; __builtin_memcpy(&s, &h, 2); return s;
}
__device__ __forceinline__ float u2f(unsigned short u){ union { unsigned int i; float f; } z; z.i = ((unsigned int)u) << 16; return z.f; }
__device__ __forceinline__ bf16x8 cvt8(float4 a, float4 b){
  return (bf16x8){f2s(a.x),f2s(a.y),f2s(a.z),f2s(a.w), f2s(b.x),f2s(b.y),f2s(b.z),f2s(b.w)};
}

// ==================== one-shot weight conversion fp32 -> bf16 (12 tensors, 11,534,336 elems) ====================
struct WSrc { const float* p[12]; };
__global__ __launch_bounds__(256) void k_cvtw(WSrc srcs, bf16* __restrict__ dst){
  const unsigned off[13] = {0u,262144u,524288u,786432u,2359296u,2883584u,4456448u,4980736u,
                            6553600u,7077888u,9175040u,11272192u,11534336u};
  size_t base = ((size_t)blockIdx.x*256 + threadIdx.x)*8;   // 8-elem chunks never span segments
  int seg = 0;
  while (seg < 11 && base >= off[seg+1]) seg++;
  const float* s = srcs.p[seg] + (base - off[seg]);
  float4 a = *(const float4*)s;
  float4 b = *(const float4*)(s + 4);
  *(bf16x8*)&dst[base] = cvt8(a, b);
}

// ==================== MFMA GEMM 128xBN: R19 LDS layout + static-index dbuf, 1 barrier/step ====================
template<typename AT, typename WT, typename CT, int ACT, int BN, int RES>
__global__ __launch_bounds__(256, BN == 64 ? 2 : 1)
void k_gemm_mfma(const AT* __restrict__ A, const WT* __restrict__ W,
                 const float* __restrict__ bias, CT* C,
                 const float* Rres, int rows, int Kd, int Nc)
{
  __shared__ short As[2][128][40];   // 80 B row stride; dbuf
  __shared__ short Bs[2][BN][40];
  constexpr int NI = BN / 32;
  int rb = blockIdx.x * 128, nb = blockIdx.y * BN;
  int tid = threadIdx.x;
  int l = tid & 63, w = tid >> 6;
  int wr = (w >> 1) * 64, wc = (w & 1) * (BN/2);
  int lr = l & 15, lk = l >> 4;
  f32x4 acc[4][NI];
  #pragma unroll
  for (int i = 0; i < 4; i++)
    #pragma unroll
    for (int j = 0; j < NI; j++)
      acc[i][j] = (f32x4){0.f, 0.f, 0.f, 0.f};
  int sr = tid >> 1;
  int sc = (tid & 1) * 16;
  bool doB = (BN == 128) || (tid < 128);
  bool doA = (rb + sr) < rows;

  float4 fa[4], fb[4];
  bf16x8 ba[2], wb[2];
  #pragma unroll
  for (int i = 0; i < 4; i++){ fa[i] = (float4){0,0,0,0}; fb[i] = (float4){0,0,0,0}; }
  ba[0] = ba[1] = wb[0] = wb[1] = (bf16x8){0,0,0,0,0,0,0,0};

  auto LOADS = [&](int k0){
    if constexpr (std::is_same<AT, float>::value){
      if (doA){
        const float4* p = (const float4*)(A + (size_t)(rb + sr)*Kd + k0 + sc);
        fa[0] = p[0]; fa[1] = p[1]; fa[2] = p[2]; fa[3] = p[3];
      }
    } else {
      if (doA){
        const bf16x8* p = (const bf16x8*)((const unsigned short*)A + (size_t)(rb + sr)*Kd + k0 + sc);
        ba[0] = p[0]; ba[1] = p[1];
      }
    }
    if (doB){
      if constexpr (std::is_same<WT, float>::value){
        const float4* p = (const float4*)(W + (size_t)(nb + sr)*Kd + k0 + sc);
        fb[0] = p[0]; fb[1] = p[1]; fb[2] = p[2]; fb[3] = p[3];
      } else {
        const bf16x8* p = (const bf16x8*)((const unsigned short*)W + (size_t)(nb + sr)*Kd + k0 + sc);
        wb[0] = p[0]; wb[1] = p[1];
      }
    }
  };
  auto STOREK = [&](int buf){
    if constexpr (std::is_same<AT, float>::value){
      *(bf16x8*)&As[buf][sr][sc]     = cvt8(fa[0], fa[1]);
      *(bf16x8*)&As[buf][sr][sc + 8] = cvt8(fa[2], fa[3]);
    } else {
      *(bf16x8*)&As[buf][sr][sc]     = ba[0];
      *(bf16x8*)&As[buf][sr][sc + 8] = ba[1];
    }
    if (doB){
      if constexpr (std::is_same<WT, float>::value){
        *(bf16x8*)&Bs[buf][sr][sc]     = cvt8(fb[0], fb[1]);
        *(bf16x8*)&Bs[buf][sr][sc + 8] = cvt8(fb[2], fb[3]);
      } else {
        *(bf16x8*)&Bs[buf][sr][sc]     = wb[0];
        *(bf16x8*)&Bs[buf][sr][sc + 8] = wb[1];
      }
    }
  };
  auto COMPUTE = [&](int buf){
    bf16x8 af[4], bf_[NI];
    #pragma unroll
    for (int mi = 0; mi < 4; mi++) af[mi]  = *(const bf16x8*)&As[buf][wr + mi*16 + lr][lk*8];
    #pragma unroll
    for (int ni = 0; ni < NI; ni++) bf_[ni] = *(const bf16x8*)&Bs[buf][wc + ni*16 + lr][lk*8];
    #pragma unroll
    for (int mi = 0; mi < 4; mi++)
      #pragma unroll
      for (int ni = 0; ni < NI; ni++)
        acc[mi][ni] = __builtin_amdgcn_mfma_f32_16x16x32_bf16(af[mi], bf_[ni], acc[mi][ni], 0, 0, 0);
  };

  int nst = Kd >> 5;                    // 16 or 64 — always even
  LOADS(0);
  STOREK(0);
  LOADS(32);
  __syncthreads();
  for (int s = 0; s < nst; s += 2){
    COMPUTE(0);
    STOREK(1);                          // regs hold tile s+1 (other buffer than current reads)
    if (s + 2 < nst) LOADS((s + 2) * 32);
    __syncthreads();
    COMPUTE(1);
    if (s + 2 < nst){
      STOREK(0);                        // regs hold tile s+2
      if (s + 3 < nst) LOADS((s + 3) * 32);
      __syncthreads();
    }
  }

  #pragma unroll
  for (int mi = 0; mi < 4; mi++){
    #pragma unroll
    for (int ni = 0; ni < NI; ni++){
      int col = nb + wc + ni*16 + lr;
      float bs = bias[col];
      #pragma unroll
      for (int r = 0; r < 4; r++){
        int row = rb + wr + mi*16 + lk*4 + r;
        if (row < rows){
          float v = acc[mi][ni][r] + bs;
          if (RES) v += Rres[(size_t)row*Nc + col];
          if (ACT == 1) v = 0.5f*v*(1.0f + erff(v*0.70710678118654752f));
          if constexpr (std::is_same<CT, float>::value) C[(size_t)row*Nc + col] = v;
          else C[(size_t)row*Nc + col] = __float2bfloat16(v);
        }
      }
    }
  }
}

// ==================== MFMA GEMM 64x64: R19 LDS layout + static-index dbuf ====================
template<typename AT, typename WT, typename CT, int ACT, int RES>
__global__ __launch_bounds__(256, 4)
void k_gemm64(const AT* __restrict__ A, const WT* __restrict__ W,
              const float* __restrict__ bias, CT* C,
              const float* Rres, int rows, int Kd, int Nc)
{
  __shared__ short As[2][64][40];
  __shared__ short Bs[2][64][40];
  int rb = blockIdx.x * 64, nb = blockIdx.y * 64;
  int tid = threadIdx.x;
  int l = tid & 63, w = tid >> 6;
  int wr = (w >> 1) * 32, wc = (w & 1) * 32;
  int lr = l & 15, lk = l >> 4;
  f32x4 acc[2][2];
  #pragma unroll
  for (int i = 0; i < 2; i++)
    #pragma unroll
    for (int j = 0; j < 2; j++)
      acc[i][j] = (f32x4){0.f, 0.f, 0.f, 0.f};
  int sr = tid >> 2;            // row 0..63, 4 threads/row
  int sc = (tid & 3) * 8;       // shorts: 0/8/16/24
  bool doA = (rb + sr) < rows;

  float4 fa[2], fw[2];
  bf16x8 ba, wb;
  fa[0] = fa[1] = fw[0] = fw[1] = (float4){0,0,0,0};
  ba = wb = (bf16x8){0,0,0,0,0,0,0,0};

  auto LOADS = [&](int k0){
    if constexpr (std::is_same<AT, float>::value){
      if (doA){
        const float4* p = (const float4*)(A + (size_t)(rb + sr)*Kd + k0 + sc);
        fa[0] = p[0]; fa[1] = p[1];
      }
    } else {
      if (doA) ba = *(const bf16x8*)((const unsigned short*)A + (size_t)(rb + sr)*Kd + k0 + sc);
    }
    if constexpr (std::is_same<WT, float>::value){
      const float4* p = (const float4*)(W + (size_t)(nb + sr)*Kd + k0 + sc);
      fw[0] = p[0]; fw[1] = p[1];
    } else {
      wb = *(const bf16x8*)((const unsigned short*)W + (size_t)(nb + sr)*Kd + k0 + sc);
    }
  };
  auto STOREK = [&](int buf){
    if constexpr (std::is_same<AT, float>::value) *(bf16x8*)&As[buf][sr][sc] = cvt8(fa[0], fa[1]);
    else                                          *(bf16x8*)&As[buf][sr][sc] = ba;
    if constexpr (std::is_same<WT, float>::value) *(bf16x8*)&Bs[buf][sr][sc] = cvt8(fw[0], fw[1]);
    else                                          *(bf16x8*)&Bs[buf][sr][sc] = wb;
  };
  auto COMPUTE = [&](int buf){
    bf16x8 af[2], bf_[2];
    #pragma unroll
    for (int mi = 0; mi < 2; mi++) af[mi]  = *(const bf16x8*)&As[buf][wr + mi*16 + lr][lk*8];
    #pragma unroll
    for (int ni = 0; ni < 2; ni++) bf_[ni] = *(const bf16x8*)&Bs[buf][wc + ni*16 + lr][lk*8];
    #pragma unroll
    for (int mi = 0; mi < 2; mi++)
      #pragma unroll
      for (int ni = 0; ni < 2; ni++)
        acc[mi][ni] = __builtin_amdgcn_mfma_f32_16x16x32_bf16(af[mi], bf_[ni], acc[mi][ni], 0, 0, 0);
  };

  int nst = Kd >> 5;                    // even
  LOADS(0);
  STOREK(0);
  LOADS(32);
  __syncthreads();
  for (int s = 0; s < nst; s += 2){
    COMPUTE(0);
    STOREK(1);
    if (s + 2 < nst) LOADS((s + 2) * 32);
    __syncthreads();
    COMPUTE(1);
    if (s + 2 < nst){
      STOREK(0);
      if (s + 3 < nst) LOADS((s + 3) * 32);
      __syncthreads();
    }
  }

  #pragma unroll
  for (int mi = 0; mi < 2; mi++){
    #pragma unroll
    for (int ni = 0; ni < 2; ni++){
      int col = nb + wc + ni*16 + lr;
      float bs = bias[col];
      #pragma unroll
      for (int r = 0; r < 4; r++){
        int row = rb + wr + mi*16 + lk*4 + r;
        if (row < rows){
          float v = acc[mi][ni][r] + bs;
          if (RES) v += Rres[(size_t)row*Nc + col];
          if (ACT == 1) v = 0.5f*v*(1.0f + erff(v*0.70710678118654752f));
          if constexpr (std::is_same<CT, float>::value) C[(size_t)row*Nc + col] = v;
          else C[(size_t)row*Nc + col] = __float2bfloat16(v);
        }
      }
    }
  }
}

// ==================== row LayerNorm (D=512), optional residual + relu. NO restrict (may run in place). ====================
template<typename XT, typename OT>
__global__ __launch_bounds__(256) void k_ln(const XT* X, const float* R,
                                            const float* g, const float* bt,
                                            OT* out, int relu)
{
  __shared__ float red[4];
  int row = blockIdx.x, t = threadIdx.x;
  size_t base = (size_t)row * 512;
  float x0, x1;
  if constexpr (std::is_same<XT, float>::value){ x0 = X[base + t]; x1 = X[base + t + 256]; }
  else { x0 = b2f(X[base + t]); x1 = b2f(X[base + t + 256]); }
  if (R){ x0 += R[base + t]; x1 += R[base + t + 256]; }
  float v = x0 + x1;
  #pragma unroll
  for (int o = 32; o > 0; o >>= 1) v += __shfl_xor(v, o);
  if ((t & 63) == 0) red[t >> 6] = v;
  __syncthreads();
  float mean = (red[0]+red[1]+red[2]+red[3]) * (1.0f/512.0f);
  float d0 = x0 - mean, d1 = x1 - mean;
  v = d0*d0 + d1*d1;
  #pragma unroll
  for (int o = 32; o > 0; o >>= 1) v += __shfl_xor(v, o);
  __syncthreads();
  if ((t & 63) == 0) red[t >> 6] = v;
  __syncthreads();
  float var = (red[0]+red[1]+red[2]+red[3]) * (1.0f/512.0f);
  float is = 1.0f / sqrtf(var + 1e-5f);
  float y0 = d0*is*g[t] + bt[t];
  float y1 = d1*is*g[t+256] + bt[t+256];
  if (relu){ y0 = fmaxf(y0, 0.0f); y1 = fmaxf(y1, 0.0f); }
  if constexpr (std::is_same<OT, float>::value){ out[base + t] = y0; out[base + t + 256] = y1; }
  else { out[base + t] = __float2bfloat16(y0); out[base + t + 256] = __float2bfloat16(y1); }
}

// ==================== bev transpose [64, 512, 256] f32 -> [16384, 512] bf16 ====================
__global__ void k_bev_tok(const float* __restrict__ bev, bf16* __restrict__ out){
  __shared__ float tile[32][33];
  int b = blockIdx.z;
  int d0 = blockIdx.x * 32;
  int p0 = blockIdx.y * 32;
  int tx = threadIdx.x, ty = threadIdx.y;
  #pragma unroll
  for (int i = 0; i < 4; i++){
    int d = d0 + ty + i*8;
    tile[ty + i*8][tx] = bev[((size_t)b*512 + d)*256 + p0 + tx];
  }
  __syncthreads();
  #pragma unroll
  for (int i = 0; i < 4; i++){
    int p = p0 + ty + i*8;
    out[((size_t)b*256 + p)*512 + d0 + tx] = __float2bfloat16(tile[tx][ty + i*8]);
  }
}

// ==================== top-K agents + invalid mask ====================
__global__ void k_topk(const float* __restrict__ labels, const float* __restrict__ states,
                       int* __restrict__ idxo, int* __restrict__ invo)
{
  __shared__ float dist[32];
  __shared__ int valid[32];
  int b = blockIdx.x, t = threadIdx.x;
  if (t < 32){
    float lab = labels[b*32 + t];
    float sg = 1.0f / (1.0f + expf(-lab));
    int va = sg > 0.05f;
    float x = states[((size_t)b*32 + t)*8 + 0];
    float y = states[((size_t)b*32 + t)*8 + 1];
    float d = sqrtf(__fadd_rn(__fmul_rn(x,x), __fmul_rn(y,y)));
    dist[t] = va ? d : INFINITY;
    valid[t] = va;
  }
  __syncthreads();
  if (t == 0){
    unsigned used = 0;
    int inv8[8]; int allinv = 1;
    for (int kk = 0; kk < 8; kk++){
      float best = INFINITY; int bi = -1;
      for (int i = 0; i < 32; i++){
        if (used & (1u << i)) continue;
        if (bi < 0 || dist[i] < best){ best = dist[i]; bi = i; }
      }
      used |= 1u << bi;
      idxo[b*8 + kk] = bi;
      inv8[kk] = !valid[bi];
      allinv &= inv8[kk];
    }
    for (int kk = 0; kk < 8; kk++) invo[b*8 + kk] = allinv ? 0 : inv8[kk];
  }
}

// ==================== gather agents f32 -> bf16 [512,512] ====================
__global__ void k_gather(const float* __restrict__ aq, const int* __restrict__ idx, bf16* __restrict__ out)
{
  int rk = blockIdx.x; int b = rk >> 3;
  int src = idx[rk] & 31;
  int t = threadIdx.x;
  size_t sbase = ((size_t)(b*32 + src))*512;
  out[(size_t)rk*512 + t]       = __float2bfloat16(aq[sbase + t]);
  out[(size_t)rk*512 + t + 256] = __float2bfloat16(aq[sbase + t + 256]);
}

// ==================== agent_kv f32 enc -> bf16 [4096,512] ====================
__global__ void k_agentkv(const float* __restrict__ enc, const float* __restrict__ step_e,
                          const float* __restrict__ role_e, bf16* __restrict__ out)
{
  int row = blockIdx.x;
  int t8 = row & 7; int bk = row >> 3;
  int tx = threadIdx.x;
  #pragma unroll
  for (int j = 0; j < 2; j++){
    int d = tx + j*256;
    out[(size_t)row*512 + d] = __float2bfloat16((enc[(size_t)bk*512 + d] + step_e[t8*512 + d]) + role_e[512 + d]);
  }
}

// ==================== sequential codebook NN scan -> tokens [B,T] ====================
__global__ __launch_bounds__(64) void k_cbscan(const float* __restrict__ gt, const float* __restrict__ cb,
                                               int* __restrict__ toks)
{
  __shared__ float cbx[512], cby[512];
  int b = blockIdx.x;
  int l = threadIdx.x;
  #pragma unroll
  for (int i = 0; i < 8; i++){
    int v = l + i*64;
    cbx[v] = cb[v*2 + 0];
    cby[v] = cb[v*2 + 1];
  }
  __syncthreads();
  float ax = 0.0f, ay = 0.0f;
  for (int t = 0; t < 8; t++){
    float px = gt[(b*8 + t)*3 + 0];
    float py = gt[(b*8 + t)*3 + 1];
    float bestv = INFINITY; int besti = 0;
    #pragma unroll
    for (int i = 0; i < 8; i++){
      int v = l*8 + i;
      float dx = __fsub_rn(__fadd_rn(ax, cbx[v]), px);
      float dy = __fsub_rn(__fadd_rn(ay, cby[v]), py);
      float d = __fadd_rn(__fmul_rn(dx,dx), __fmul_rn(dy,dy));
      if (d < bestv || (d == bestv && v < besti)){ bestv = d; besti = v; }
    }
    #pragma unroll
    for (int o = 32; o > 0; o >>= 1){
      float ov = __shfl_xor(bestv, o);
      int oi = __shfl_xor(besti, o);
      if (ov < bestv || (ov == bestv && oi < besti)){ bestv = ov; besti = oi; }
    }
    ax = __fadd_rn(ax, cbx[besti]);
    ay = __fadd_rn(ay, cby[besti]);
    if (l == 0) toks[b*8 + t] = besti;
  }
}

// ==================== teacher-forced embedding -> egoq f32 ====================
__global__ void k_embed(const int* __restrict__ toks, const float* __restrict__ ebase,
                        const float* __restrict__ tok_emb, const float* __restrict__ step_e,
                        const float* __restrict__ mode_e, const float* __restrict__ role_e,
                        const float* __restrict__ bos_e, float* __restrict__ out)
{
  int row = blockIdx.x;
  int t = row & 7; int bm = row >> 3; int m = bm % 20; int b = bm / 20;
  int tok = (t == 0) ? 0 : (toks[b*8 + t - 1] & 511);
  int tx = threadIdx.x;
  #pragma unroll
  for (int j = 0; j < 2; j++){
    int d = tx + j*256;
    float base = (t == 0) ? (bos_e[d] + ebase[(size_t)b*512 + d])
                          : tok_emb[(size_t)tok*512 + d];
    out[(size_t)row*512 + d] = ((base + step_e[t*512 + d]) + role_e[d]) + mode_e[m*512 + d];
  }
}

// ==================== temporal causal attention (QKV bf16 [rows,1536] -> O bf16) ====================
__global__ __launch_bounds__(64) void k_tattn(const bf16* __restrict__ QKV, bf16* __restrict__ O)
{
  __shared__ float q[8][65], k[8][65], v[8][65], w[8][9];
  int h = blockIdx.x & 7; int bm = blockIdx.x >> 3;
  int l = threadIdx.x;
  for (int t = 0; t < 8; t++){
    size_t base = ((size_t)(bm*8 + t))*1536 + h*64 + l;
    q[t][l] = b2f(QKV[base]);
    k[t][l] = b2f(QKV[base + 512]);
    v[t][l] = b2f(QKV[base + 1024]);
  }
  __syncthreads();
  int tq = l >> 3, tk = l & 7;
  float s = -INFINITY;
  if (tk <= tq){
    float acc = 0.0f;
    #pragma unroll
    for (int e = 0; e < 64; e++) acc += q[tq][e]*k[tk][e];
    s = acc * 0.125f;
  }
  float mx = s;
  #pragma unroll
  for (int o = 1; o < 8; o <<= 1) mx = fmaxf(mx, __shfl_xor(mx, o));
  float ex = (tk <= tq) ? expf(s - mx) : 0.0f;
  float sm = ex;
  #pragma unroll
  for (int o = 1; o < 8; o <<= 1) sm += __shfl_xor(sm, o);
  w[tq][tk] = ex / sm;
  __syncthreads();
  #pragma unroll
  for (int t2 = 0; t2 < 8; t2++){
    float acc = 0.0f;
    #pragma unroll
    for (int tk2 = 0; tk2 < 8; tk2++) acc += w[t2][tk2]*v[tk2][l];
    O[((size_t)(bm*8 + t2))*512 + h*64 + l] = __float2bfloat16(acc);
  }
}

// ==================== ego-to-agent cross-attention; KV interleaved [4096,1024] (K|V) ====================
__global__ __launch_bounds__(64) void k_eattn(const bf16* __restrict__ Q, const bf16* __restrict__ KV,
                                              const int* __restrict__ inv,
                                              bf16* __restrict__ O, int row0)
{
  int blk = blockIdx.x;
  int h = blockIdx.y;
  int grow = row0 + blk;
  int t = grow & 7;
  int b = grow / 160;
  int l = threadIdx.x;
  size_t qoff = (size_t)blk*512 + h*64 + l;
  float q = b2f(Q[qoff]);
  float s[8];
  #pragma unroll
  for (int k = 0; k < 8; k++){
    float p = q * b2f(KV[((size_t)((b*8 + k)*8 + t))*1024 + h*64 + l]);
    #pragma unroll
    for (int o = 32; o > 0; o >>= 1) p += __shfl_xor(p, o);
    s[k] = p * 0.125f;
  }
  float mx = -INFINITY;
  #pragma unroll
  for (int k = 0; k < 8; k++){
    if (inv[b*8 + k]) s[k] = -INFINITY;
    mx = fmaxf(mx, s[k]);
  }
  float sum = 0.0f, w[8];
  #pragma unroll
  for (int k = 0; k < 8; k++){ w[k] = expf(s[k] - mx); sum += w[k]; }
  float rs = 1.0f / sum;
  float acc = 0.0f;
  #pragma unroll
  for (int k = 0; k < 8; k++)
    acc += (w[k]*rs) * b2f(KV[((size_t)((b*8 + k)*8 + t))*1024 + 512 + h*64 + l]);
  O[qoff] = __float2bfloat16(acc);
}

// ==================== BEV cross-attention v5 (MFMA flash-style); bl spans grid.x ====================
__global__ __launch_bounds__(256, 2) void k_vattn(const bf16* __restrict__ Q, const bf16* __restrict__ KV,
                                                  bf16* __restrict__ O)
{
  __shared__ unsigned short Ks[256][72];   // P [32][264] aliases this after scores
  __shared__ unsigned short Vt[64][264];   // V transposed [e][key]
  __shared__ float red[2][2][16];
  unsigned short (*P_lds)[264] = (unsigned short (*)[264])&Ks[0][0];

  int bl = blockIdx.x, h = blockIdx.y, qz = blockIdx.z;
  int tid = threadIdx.x;
  const unsigned short* KVr = (const unsigned short*)KV;

  {
    const uint4* ksrc = (const uint4*)&KVr[((size_t)(bl*256 + tid))*1024 + h*64];
    const uint4* vsrc = (const uint4*)&KVr[((size_t)(bl*256 + tid))*1024 + 512 + h*64];
    #pragma unroll
    for (int i = 0; i < 8; i++){
      uint4 kx = ksrc[i];
      *(uint4*)&Ks[tid][i*8] = kx;
    }
    #pragma unroll
    for (int i = 0; i < 8; i++){
      uint4 vx = vsrc[i];
      unsigned short vs[8];
      __builtin_memcpy(vs, &vx, 16);
      #pragma unroll
      for (int j = 0; j < 8; j++) Vt[i*8 + j][tid] = vs[j];
    }
  }
  __syncthreads();

  int w = tid >> 6, l = tid & 63, lr = l & 15, lk = l >> 4;
  int mt = w >> 1, ch = w & 1;

  int qrow = bl*160 + qz*32 + mt*16 + lr;
  const unsigned short* Qr = (const unsigned short*)Q;
  bf16x8 qf0 = *(const bf16x8*)&Qr[(size_t)qrow*512 + h*64 + lk*8];
  bf16x8 qf1 = *(const bf16x8*)&Qr[(size_t)qrow*512 + h*64 + 32 + lk*8];

  f32x4 sacc[8];
  #pragma unroll
  for (int nt = 0; nt < 8; nt++) sacc[nt] = (f32x4){0.f,0.f,0.f,0.f};
  #pragma unroll
  for (int nt = 0; nt < 8; nt++){
    int key0 = ch*128 + nt*16 + lr;
    bf16x8 kf0 = *(const bf16x8*)&Ks[key0][lk*8];
    bf16x8 kf1 = *(const bf16x8*)&Ks[key0][32 + lk*8];
    sacc[nt] = __builtin_amdgcn_mfma_f32_16x16x32_bf16(qf0, kf0, sacc[nt], 0, 0, 0);
    sacc[nt] = __builtin_amdgcn_mfma_f32_16x16x32_bf16(qf1, kf1, sacc[nt], 0, 0, 0);
  }

  float rmax[4] = {-INFINITY, -INFINITY, -INFINITY, -INFINITY};
  #pragma unroll
  for (int nt = 0; nt < 8; nt++)
    #pragma unroll
    for (int r = 0; r < 4; r++){
      float v = sacc[nt][r] * 0.125f;
      sacc[nt][r] = v;
      rmax[r] = fmaxf(rmax[r], v);
    }
  #pragma unroll
  for (int r = 0; r < 4; r++){
    #pragma unroll
    for (int o = 1; o < 16; o <<= 1) rmax[r] = fmaxf(rmax[r], __shfl_xor(rmax[r], o));
  }
  if (lr == 0){
    #pragma unroll
    for (int r = 0; r < 4; r++) red[mt][ch][lk*4 + r] = rmax[r];
  }
  __syncthreads();
  float m4[4];
  #pragma unroll
  for (int r = 0; r < 4; r++) m4[r] = fmaxf(red[mt][0][lk*4 + r], red[mt][1][lk*4 + r]);
  float rsum[4] = {0.f, 0.f, 0.f, 0.f};
  #pragma unroll
  for (int nt = 0; nt < 8; nt++){
    #pragma unroll
    for (int r = 0; r < 4; r++){
      float e = expf(sacc[nt][r] - m4[r]);
      rsum[r] += e;
      P_lds[mt*16 + lk*4 + r][ch*128 + nt*16 + lr] = (unsigned short)f2s(e);
    }
  }
  #pragma unroll
  for (int r = 0; r < 4; r++){
    #pragma unroll
    for (int o = 1; o < 16; o <<= 1) rsum[r] += __shfl_xor(rsum[r], o);
  }
  __syncthreads();
  if (lr == 0){
    #pragma unroll
    for (int r = 0; r < 4; r++) red[mt][ch][lk*4 + r] = rsum[r];
  }
  __syncthreads();
  float rcp4[4];
  #pragma unroll
  for (int r = 0; r < 4; r++) rcp4[r] = 1.0f / (red[mt][0][lk*4 + r] + red[mt][1][lk*4 + r]);

  f32x4 oacc0 = (f32x4){0.f,0.f,0.f,0.f};
  f32x4 oacc1 = (f32x4){0.f,0.f,0.f,0.f};
  #pragma unroll
  for (int kk = 0; kk < 8; kk++){
    bf16x8 pf  = *(const bf16x8*)&P_lds[mt*16 + lr][kk*32 + lk*8];
    bf16x8 vf0 = *(const bf16x8*)&Vt[ch*32 + lr][kk*32 + lk*8];
    bf16x8 vf1 = *(const bf16x8*)&Vt[ch*32 + 16 + lr][kk*32 + lk*8];
    oacc0 = __builtin_amdgcn_mfma_f32_16x16x32_bf16(pf, vf0, oacc0, 0, 0, 0);
    oacc1 = __builtin_amdgcn_mfma_f32_16x16x32_bf16(pf, vf1, oacc1, 0, 0, 0);
  }

  {
    size_t obase = ((size_t)(bl*160 + qz*32 + mt*16 + lk*4))*512 + h*64 + ch*32 + lr;
    #pragma unroll
    for (int r = 0; r < 4; r++){
      O[obase + (size_t)r*512]      = __float2bfloat16(oacc0[r] * rcp4[r]);
      O[obase + (size_t)r*512 + 16] = __float2bfloat16(oacc1[r] * rcp4[r]);
    }
  }
}

// ==================== launchers ====================
template<typename AT, typename CT, int ACT, int BN, int RES>
static inline void launch_gemm(bool wbf, const AT* A, const float* Wf, const bf16* Wb,
                               const float* bias, CT* C, const float* Rr,
                               int rows, int Kd, int Nc, hipStream_t st){
  dim3 g((rows + 127)/128, Nc/BN);
  if (wbf) k_gemm_mfma<AT,bf16,CT,ACT,BN,RES><<<g,256,0,st>>>(A, Wb, bias, C, Rr, rows, Kd, Nc);
  else     k_gemm_mfma<AT,float,CT,ACT,BN,RES><<<g,256,0,st>>>(A, Wf, bias, C, Rr, rows, Kd, Nc);
}
template<typename AT, typename CT, int ACT, int RES>
static inline void launch_gemm64(bool wbf, const AT* A, const float* Wf, const bf16* Wb,
                                 const float* bias, CT* C, const float* Rr,
                                 int rows, int Kd, int Nc, hipStream_t st){
  dim3 g((rows + 63)/64, Nc/64);
  if (wbf) k_gemm64<AT,bf16,CT,ACT,RES><<<g,256,0,st>>>(A, Wb, bias, C, Rr, rows, Kd, Nc);
  else     k_gemm64<AT,float,CT,ACT,RES><<<g,256,0,st>>>(A, Wf, bias, C, Rr, rows, Kd, Nc);
}

extern "C" void kernel_launch(void* const* d_in, const int* in_sizes, int n_in,
                              void* d_out, int out_size, void* d_ws, size_t ws_size,
                              hipStream_t stream)
{
  (void)in_sizes; (void)n_in; (void)out_size;
  const float* ego_query    = (const float*)d_in[0];
  const float* agents_query = (const float*)d_in[1];
  const float* bev_feature  = (const float*)d_in[2];
  const float* agent_states = (const float*)d_in[3];
  const float* agent_labels = (const float*)d_in[4];
  const float* gt_traj      = (const float*)d_in[5];
  const float* codebook     = (const float*)d_in[6];
  const float* ego_ctx_w    = (const float*)d_in[7];
  const float* ego_ctx_b    = (const float*)d_in[8];
  const float* ego_ctx_g    = (const float*)d_in[9];
  const float* ego_ctx_beta = (const float*)d_in[10];
  const float* bevproj_w    = (const float*)d_in[11];
  const float* bevproj_b    = (const float*)d_in[12];
  const float* bevproj_g    = (const float*)d_in[13];
  const float* bevproj_beta = (const float*)d_in[14];
  const float* agent_w      = (const float*)d_in[15];
  const float* agent_b      = (const float*)d_in[16];
  const float* agent_g      = (const float*)d_in[17];
  const float* agent_beta   = (const float*)d_in[18];
  const float* tok_emb      = (const float*)d_in[19];
  const float* step_e       = (const float*)d_in[20];
  const float* mode_e       = (const float*)d_in[21];
  const float* role_e       = (const float*)d_in[22];
  const float* bos_e        = (const float*)d_in[23];
  const float* t_qkv_w      = (const float*)d_in[24];
  const float* t_qkv_b      = (const float*)d_in[25];
  const float* t_out_w      = (const float*)d_in[26];
  const float* t_out_b      = (const float*)d_in[27];
  const float* t_g          = (const float*)d_in[28];
  const float* t_beta       = (const float*)d_in[29];
  const float* e_qkv_w      = (const float*)d_in[30];
  const float* e_qkv_b      = (const float*)d_in[31];
  const float* e_out_w      = (const float*)d_in[32];
  const float* e_out_b      = (const float*)d_in[33];
  const float* e_g          = (const float*)d_in[34];
  const float* e_beta       = (const float*)d_in[35];
  const float* v_qkv_w      = (const float*)d_in[36];
  const float* v_qkv_b      = (const float*)d_in[37];
  const float* v_out_w      = (const float*)d_in[38];
  const float* v_out_b      = (const float*)d_in[39];
  const float* v_g          = (const float*)d_in[40];
  const float* v_beta       = (const float*)d_in[41];
  const float* ffn_w1       = (const float*)d_in[42];
  const float* ffn_b1       = (const float*)d_in[43];
  const float* ffn_w2       = (const float*)d_in[44];
  const float* ffn_b2       = (const float*)d_in[45];
  const float* ffn_g        = (const float*)d_in[46];
  const float* ffn_beta     = (const float*)d_in[47];
  const float* head_w       = (const float*)d_in[48];
  const float* head_b       = (const float*)d_in[49];

  // ---- workspace tiers: small 46.3 / big 67.3 / big2 100.8 / big3 123.9 MB (bf16 weights) ----
  const size_t NEEDED       = 46274560;
  const size_t NEEDED_BIG   = 67248128;
  const size_t NEEDED_BIG2  = 100800512;
  const size_t NEEDED_BIG3  = 123869184;
  if (ws_size < NEEDED) return;
  bool big  = ws_size >= NEEDED_BIG;
  bool big2 = ws_size >= NEEDED_BIG2;
  bool big3 = ws_size >= NEEDED_BIG3;
  int RC  = big ? 10240 : 5120;
  int NCH = big ? 1 : 2;

  char* WB = (char*)d_ws;
  bf16*  bevtok = (bf16*)(WB + 0);          // [16384,512] bf16 persistent
  bf16*  akv    = (bf16*)(WB + 16777216);   // [4096,512] bf16 persistent
  float* ebase  = (float*)(WB + 20971520);  // [64,512] f32
  char*  ARENA  = WB + 21102592;
  bf16*  KVb    = (bf16*)(WB + 37879808);   // [4096,1024] bf16
  bf16*  KVbig  = (bf16*)(WB + 67239936);   // [16384,1024] bf16 (big2+)
  bf16*  WCV    = (bf16*)(WB + 100800512);  // [11,534,336] bf16 converted weights (big3)
  size_t tk0    = big2 ? 100794368 : (big ? 67239936 : 46268416);
  int*   toks   = (int*)(WB + tk0);
  int*   idxb   = (int*)(WB + tk0 + 2048);
  int*   invb   = (int*)(WB + tk0 + 4096);
  size_t oe_off = big ? 31457280 : 5242880;

  float* egoq = (float*)d_out;   // [10240,512] f32 residual stream lives in d_out

  // converted-weight element offsets
  bf16* c_bevproj = WCV + 0;
  bf16* c_ego     = WCV + 262144;
  bf16* c_agent   = WCV + 524288;
  bf16* c_tqkv    = WCV + 786432;
  bf16* c_tout    = WCV + 2359296;
  bf16* c_eqkv    = WCV + 2883584;
  bf16* c_eout    = WCV + 4456448;
  bf16* c_vqkv    = WCV + 4980736;
  bf16* c_vout    = WCV + 6553600;
  bf16* c_ffn1    = WCV + 7077888;
  bf16* c_ffn2    = WCV + 9175040;
  bf16* c_head    = WCV + 11272192;

  if (big3){
    WSrc src;
    src.p[0] = bevproj_w; src.p[1] = ego_ctx_w; src.p[2] = agent_w;  src.p[3] = t_qkv_w;
    src.p[4] = t_out_w;   src.p[5] = e_qkv_w;   src.p[6] = e_out_w;  src.p[7] = v_qkv_w;
    src.p[8] = v_out_w;   src.p[9] = ffn_w1;    src.p[10] = ffn_w2;  src.p[11] = head_w;
    k_cvtw<<<5632, 256, 0, stream>>>(src, WCV);
  }

  #define GEMM(AT,CT,ACT,BN,RES, Ap, Wf, Wb, Bp,Cp,Rp, R,K,N) \
    launch_gemm<AT,CT,ACT,BN,RES>(big3, Ap, Wf, Wb, Bp, Cp, Rp, R, K, N, stream)
  #define GEMM64(AT,CT,ACT,RES, Ap, Wf, Wb, Bp,Cp,Rp, R,K,N) \
    launch_gemm64<AT,CT,ACT,RES>(big3, Ap, Wf, Wb, Bp, Cp, Rp, R, K, N, stream)

  // --- BEV tokens ONCE ---
  {
    bf16* raw = (bf16*)ARENA;   // [16384,512]
    k_bev_tok<<<dim3(16, 8, 64), dim3(32, 8), 0, stream>>>(bev_feature, raw);
    GEMM64(bf16,bf16,0,0, raw, bevproj_w, c_bevproj, bevproj_b, bevtok, nullptr, 16384, 512, 512);
    k_ln<bf16,bf16><<<16384, 256, 0, stream>>>(bevtok, nullptr, bevproj_g, bevproj_beta, bevtok, 1);
  }

  // --- ego base ---
  GEMM64(float,float,0,0, ego_query, ego_ctx_w, c_ego, ego_ctx_b, (float*)ARENA, nullptr, 64, 512, 512);
  k_ln<float,float><<<64, 256, 0, stream>>>((float*)ARENA, nullptr, ego_ctx_g, ego_ctx_beta, ebase, 1);

  // --- agents ---
  k_topk<<<64, 64, 0, stream>>>(agent_labels, agent_states, idxb, invb);
  {
    bf16*  gat = (bf16*)ARENA;                   // [512,512] bf16
    float* enc = (float*)(ARENA + 524288);       // [512,512] f32
    k_gather<<<512, 256, 0, stream>>>(agents_query, idxb, gat);
    GEMM64(bf16,float,0,0, gat, agent_w, c_agent, agent_b, enc, nullptr, 512, 512, 512);
    k_ln<float,float><<<512, 256, 0, stream>>>(enc, nullptr, agent_g, agent_beta, enc, 1);
    k_agentkv<<<4096, 256, 0, stream>>>(enc, step_e, role_e, akv);
  }

  // --- tokens + embedding ---
  k_cbscan<<<64, 64, 0, stream>>>(gt_traj, codebook, toks);
  k_embed<<<10240, 256, 0, stream>>>(toks, ebase, tok_emb, step_e, mode_e, role_e, bos_e, egoq);

  for (int i = 0; i < 2; i++){
    // ---- temporal self-attention ----
    {
      bf16* QKV = (bf16*)ARENA;                 // [RC,1536]
      bf16* Ot  = big ? (bf16*)(ARENA + oe_off) : KVb;   // [RC,512]
      for (int c = 0; c < NCH; c++){
        float* eg = egoq + (size_t)c*RC*512;
        GEMM(float,bf16,0,128,0, eg, t_qkv_w + (size_t)i*786432, c_tqkv + (size_t)i*786432,
             t_qkv_b + i*1536, QKV, nullptr, RC, 512, 1536);
        k_tattn<<<RC, 64, 0, stream>>>(QKV, Ot);
        GEMM64(bf16,float,0,1, Ot, t_out_w + (size_t)i*262144, c_tout + (size_t)i*262144,
             t_out_b + i*512, eg, eg, RC, 512, 512);
      }
      k_ln<float,float><<<10240, 256, 0, stream>>>(egoq, nullptr, t_g + i*512, t_beta + i*512, egoq, 0);
    }
    // ---- ego-to-agent cross-attention ----
    {
      const float* eqw = e_qkv_w + (size_t)i*786432;
      bf16*        eqc = c_eqkv + (size_t)i*786432;
      const float* eqb = e_qkv_b + i*1536;
      bf16* Qe = (bf16*)ARENA;                  // [RC,512]
      bf16* Oe = (bf16*)(ARENA + oe_off);       // [RC,512]
      GEMM64(bf16,bf16,0,0, akv, eqw + 262144, eqc + 262144, eqb + 512, KVb, nullptr, 4096, 512, 1024);
      for (int c = 0; c < NCH; c++){
        float* eg = egoq + (size_t)c*RC*512;
        GEMM64(float,bf16,0,0, eg, eqw, eqc, eqb, Qe, nullptr, RC, 512, 512);
        k_eattn<<<dim3(RC, 8), 64, 0, stream>>>(Qe, KVb, invb, Oe, c*RC);
        GEMM64(bf16,float,0,1, Oe, e_out_w + (size_t)i*262144, c_eout + (size_t)i*262144,
             e_out_b + i*512, eg, eg, RC, 512, 512);
      }
      k_ln<float,float><<<10240, 256, 0, stream>>>(egoq, nullptr, e_g + i*512, e_beta + i*512, egoq, 0);
    }
    // ---- BEV cross-attention ----
    {
      const float* vqw = v_qkv_w + (size_t)i*786432;
      bf16*        vqc = c_vqkv + (size_t)i*786432;
      const float* vqb = v_qkv_b + i*1536;
      if (big2){
        bf16* Qv = (bf16*)ARENA;                  // [10240,512]
        bf16* Ov = (bf16*)(ARENA + 10485760);     // [10240,512]
        GEMM64(bf16,bf16,0,0, bevtok, vqw + 262144, vqc + 262144, vqb + 512, KVbig, nullptr, 16384, 512, 1024);
        GEMM64(float,bf16,0,0, egoq, vqw, vqc, vqb, Qv, nullptr, 10240, 512, 512);
        k_vattn<<<dim3(64, 8, 5), 256, 0, stream>>>(Qv, KVbig, Ov);
        GEMM64(bf16,float,0,1, Ov, v_out_w + (size_t)i*262144, c_vout + (size_t)i*262144,
             v_out_b + i*512, egoq, egoq, 10240, 512, 512);
      } else {
        bf16* Qv = (bf16*)ARENA;                  // [2560,512]
        bf16* Ov = (bf16*)(ARENA + 2621440);      // [2560,512]
        for (int gidx = 0; gidx < 4; gidx++){
          float* eg = egoq + (size_t)gidx*2560*512;
          GEMM64(bf16,bf16,0,0, bevtok + (size_t)gidx*4096*512, vqw + 262144, vqc + 262144,
               vqb + 512, KVb, nullptr, 4096, 512, 1024);
          GEMM64(float,bf16,0,0, eg, vqw, vqc, vqb, Qv, nullptr, 2560, 512, 512);
          k_vattn<<<dim3(16, 8, 5), 256, 0, stream>>>(Qv, KVb, Ov);
          GEMM64(bf16,float,0,1, Ov, v_out_w + (size_t)i*262144, c_vout + (size_t)i*262144,
               v_out_b + i*512, eg, eg, 2560, 512, 512);
        }
      }
      k_ln<float,float><<<10240, 256, 0, stream>>>(egoq, nullptr, v_g + i*512, v_beta + i*512, egoq, 0);
    }
    // ---- FFN ----
    {
      bf16* hid = (bf16*)ARENA;   // [RC,2048]
      for (int c = 0; c < NCH; c++){
        float* eg = egoq + (size_t)c*RC*512;
        GEMM(float,bf16,1,128,0, eg, ffn_w1 + (size_t)i*1048576, c_ffn1 + (size_t)i*1048576,
             ffn_b1 + i*2048, hid, nullptr, RC, 512, 2048);
        GEMM64(bf16,float,0,1, hid, ffn_w2 + (size_t)i*1048576, c_ffn2 + (size_t)i*1048576,
             ffn_b2 + i*512, eg, eg, RC, 2048, 512);
      }
      if (i == 0){
        k_ln<float,float><<<10240, 256, 0, stream>>>(egoq, nullptr, ffn_g, ffn_beta, egoq, 0);
      } else {
        k_ln<float,bf16><<<10240, 256, 0, stream>>>(egoq, nullptr, ffn_g + 512, ffn_beta + 512, (bf16*)ARENA, 0);
      }
    }
  }

  // --- head ---
  GEMM64(bf16,float,0,0, (bf16*)ARENA, head_w, c_head, head_b, (float*)d_out, nullptr, 10240, 512, 512);
  #undef GEMM
  #undef GEMM64
}

// Round 23
// 990.236 us; speedup vs baseline: 1.0828x; 1.0145x over previous
//
#include <hip/hip_runtime.h>
#include <hip/hip_bf16.h>
#include <math.h>
#include <type_traits>

typedef __hip_bfloat16 bf16;
typedef __attribute__((ext_vector_type(8))) short bf16x8;
typedef __attribute__((ext_vector_type(4))) float f32x4;

__device__ __forceinline__ float b2f(bf16 x){ return __bfloat162float(x); }
__device__ __forceinline__ short f2s(float f){
  bf16 h = __float2bfloat16(f);
  short s; __builtin_memcpy(&s, &h, 2); return s;
}
__device__ __forceinline__ float u2f(unsigned short u){ union { unsigned int i; float f; } z; z.i = ((unsigned int)u) << 16; return z.f; }
__device__ __forceinline__ bf16x8 cvt8(float4 a, float4 b){
  return (bf16x8){f2s(a.x),f2s(a.y),f2s(a.z),f2s(a.w), f2s(b.x),f2s(b.y),f2s(b.z),f2s(b.w)};
}

// ==================== one-shot weight conversion fp32 -> bf16 (12 tensors, 11,534,336 elems) ====================
struct WSrc { const float* p[12]; };
__global__ __launch_bounds__(256) void k_cvtw(WSrc srcs, bf16* __restrict__ dst){
  const unsigned off[13] = {0u,262144u,524288u,786432u,2359296u,2883584u,4456448u,4980736u,
                            6553600u,7077888u,9175040u,11272192u,11534336u};
  size_t base = ((size_t)blockIdx.x*256 + threadIdx.x)*8;   // 8-elem chunks never span segments
  int seg = 0;
  while (seg < 11 && base >= off[seg+1]) seg++;
  const float* s = srcs.p[seg] + (base - off[seg]);
  float4 a = *(const float4*)s;
  float4 b = *(const float4*)(s + 4);
  *(bf16x8*)&dst[base] = cvt8(a, b);
}

// ==================== MFMA GEMM 128xBN: R19 LDS layout + static-index dbuf, 1 barrier/step ====================
// launch_bounds min-waves raised to 4 (VGPR<=128 target; measured 72) to push allocator toward 4 blocks/CU.
template<typename AT, typename WT, typename CT, int ACT, int BN, int RES>
__global__ __launch_bounds__(256, BN == 64 ? 2 : 4)
void k_gemm_mfma(const AT* __restrict__ A, const WT* __restrict__ W,
                 const float* __restrict__ bias, CT* C,
                 const float* Rres, int rows, int Kd, int Nc)
{
  __shared__ short As[2][128][40];   // 80 B row stride; dbuf
  __shared__ short Bs[2][BN][40];
  constexpr int NI = BN / 32;
  int rb = blockIdx.x * 128, nb = blockIdx.y * BN;
  int tid = threadIdx.x;
  int l = tid & 63, w = tid >> 6;
  int wr = (w >> 1) * 64, wc = (w & 1) * (BN/2);
  int lr = l & 15, lk = l >> 4;
  f32x4 acc[4][NI];
  #pragma unroll
  for (int i = 0; i < 4; i++)
    #pragma unroll
    for (int j = 0; j < NI; j++)
      acc[i][j] = (f32x4){0.f, 0.f, 0.f, 0.f};
  int sr = tid >> 1;
  int sc = (tid & 1) * 16;
  bool doB = (BN == 128) || (tid < 128);
  bool doA = (rb + sr) < rows;

  float4 fa[4], fb[4];
  bf16x8 ba[2], wb[2];
  #pragma unroll
  for (int i = 0; i < 4; i++){ fa[i] = (float4){0,0,0,0}; fb[i] = (float4){0,0,0,0}; }
  ba[0] = ba[1] = wb[0] = wb[1] = (bf16x8){0,0,0,0,0,0,0,0};

  auto LOADS = [&](int k0){
    if constexpr (std::is_same<AT, float>::value){
      if (doA){
        const float4* p = (const float4*)(A + (size_t)(rb + sr)*Kd + k0 + sc);
        fa[0] = p[0]; fa[1] = p[1]; fa[2] = p[2]; fa[3] = p[3];
      }
    } else {
      if (doA){
        const bf16x8* p = (const bf16x8*)((const unsigned short*)A + (size_t)(rb + sr)*Kd + k0 + sc);
        ba[0] = p[0]; ba[1] = p[1];
      }
    }
    if (doB){
      if constexpr (std::is_same<WT, float>::value){
        const float4* p = (const float4*)(W + (size_t)(nb + sr)*Kd + k0 + sc);
        fb[0] = p[0]; fb[1] = p[1]; fb[2] = p[2]; fb[3] = p[3];
      } else {
        const bf16x8* p = (const bf16x8*)((const unsigned short*)W + (size_t)(nb + sr)*Kd + k0 + sc);
        wb[0] = p[0]; wb[1] = p[1];
      }
    }
  };
  auto STOREK = [&](int buf){
    if constexpr (std::is_same<AT, float>::value){
      *(bf16x8*)&As[buf][sr][sc]     = cvt8(fa[0], fa[1]);
      *(bf16x8*)&As[buf][sr][sc + 8] = cvt8(fa[2], fa[3]);
    } else {
      *(bf16x8*)&As[buf][sr][sc]     = ba[0];
      *(bf16x8*)&As[buf][sr][sc + 8] = ba[1];
    }
    if (doB){
      if constexpr (std::is_same<WT, float>::value){
        *(bf16x8*)&Bs[buf][sr][sc]     = cvt8(fb[0], fb[1]);
        *(bf16x8*)&Bs[buf][sr][sc + 8] = cvt8(fb[2], fb[3]);
      } else {
        *(bf16x8*)&Bs[buf][sr][sc]     = wb[0];
        *(bf16x8*)&Bs[buf][sr][sc + 8] = wb[1];
      }
    }
  };
  auto COMPUTE = [&](int buf){
    bf16x8 af[4], bf_[NI];
    #pragma unroll
    for (int mi = 0; mi < 4; mi++) af[mi]  = *(const bf16x8*)&As[buf][wr + mi*16 + lr][lk*8];
    #pragma unroll
    for (int ni = 0; ni < NI; ni++) bf_[ni] = *(const bf16x8*)&Bs[buf][wc + ni*16 + lr][lk*8];
    #pragma unroll
    for (int mi = 0; mi < 4; mi++)
      #pragma unroll
      for (int ni = 0; ni < NI; ni++)
        acc[mi][ni] = __builtin_amdgcn_mfma_f32_16x16x32_bf16(af[mi], bf_[ni], acc[mi][ni], 0, 0, 0);
  };

  int nst = Kd >> 5;                    // 16 or 64 — always even
  LOADS(0);
  STOREK(0);
  LOADS(32);
  __syncthreads();
  for (int s = 0; s < nst; s += 2){
    COMPUTE(0);
    STOREK(1);                          // regs hold tile s+1 (other buffer than current reads)
    if (s + 2 < nst) LOADS((s + 2) * 32);
    __syncthreads();
    COMPUTE(1);
    if (s + 2 < nst){
      STOREK(0);                        // regs hold tile s+2
      if (s + 3 < nst) LOADS((s + 3) * 32);
      __syncthreads();
    }
  }

  #pragma unroll
  for (int mi = 0; mi < 4; mi++){
    #pragma unroll
    for (int ni = 0; ni < NI; ni++){
      int col = nb + wc + ni*16 + lr;
      float bs = bias[col];
      #pragma unroll
      for (int r = 0; r < 4; r++){
        int row = rb + wr + mi*16 + lk*4 + r;
        if (row < rows){
          float v = acc[mi][ni][r] + bs;
          if (RES) v += Rres[(size_t)row*Nc + col];
          if (ACT == 1) v = 0.5f*v*(1.0f + erff(v*0.70710678118654752f));
          if constexpr (std::is_same<CT, float>::value) C[(size_t)row*Nc + col] = v;
          else C[(size_t)row*Nc + col] = __float2bfloat16(v);
        }
      }
    }
  }
}

// ==================== MFMA GEMM 64x64: R19 LDS layout + static-index dbuf ====================
template<typename AT, typename WT, typename CT, int ACT, int RES>
__global__ __launch_bounds__(256, 4)
void k_gemm64(const AT* __restrict__ A, const WT* __restrict__ W,
              const float* __restrict__ bias, CT* C,
              const float* Rres, int rows, int Kd, int Nc)
{
  __shared__ short As[2][64][40];
  __shared__ short Bs[2][64][40];
  int rb = blockIdx.x * 64, nb = blockIdx.y * 64;
  int tid = threadIdx.x;
  int l = tid & 63, w = tid >> 6;
  int wr = (w >> 1) * 32, wc = (w & 1) * 32;
  int lr = l & 15, lk = l >> 4;
  f32x4 acc[2][2];
  #pragma unroll
  for (int i = 0; i < 2; i++)
    #pragma unroll
    for (int j = 0; j < 2; j++)
      acc[i][j] = (f32x4){0.f, 0.f, 0.f, 0.f};
  int sr = tid >> 2;            // row 0..63, 4 threads/row
  int sc = (tid & 3) * 8;       // shorts: 0/8/16/24
  bool doA = (rb + sr) < rows;

  float4 fa[2], fw[2];
  bf16x8 ba, wb;
  fa[0] = fa[1] = fw[0] = fw[1] = (float4){0,0,0,0};
  ba = wb = (bf16x8){0,0,0,0,0,0,0,0};

  auto LOADS = [&](int k0){
    if constexpr (std::is_same<AT, float>::value){
      if (doA){
        const float4* p = (const float4*)(A + (size_t)(rb + sr)*Kd + k0 + sc);
        fa[0] = p[0]; fa[1] = p[1];
      }
    } else {
      if (doA) ba = *(const bf16x8*)((const unsigned short*)A + (size_t)(rb + sr)*Kd + k0 + sc);
    }
    if constexpr (std::is_same<WT, float>::value){
      const float4* p = (const float4*)(W + (size_t)(nb + sr)*Kd + k0 + sc);
      fw[0] = p[0]; fw[1] = p[1];
    } else {
      wb = *(const bf16x8*)((const unsigned short*)W + (size_t)(nb + sr)*Kd + k0 + sc);
    }
  };
  auto STOREK = [&](int buf){
    if constexpr (std::is_same<AT, float>::value) *(bf16x8*)&As[buf][sr][sc] = cvt8(fa[0], fa[1]);
    else                                          *(bf16x8*)&As[buf][sr][sc] = ba;
    if constexpr (std::is_same<WT, float>::value) *(bf16x8*)&Bs[buf][sr][sc] = cvt8(fw[0], fw[1]);
    else                                          *(bf16x8*)&Bs[buf][sr][sc] = wb;
  };
  auto COMPUTE = [&](int buf){
    bf16x8 af[2], bf_[2];
    #pragma unroll
    for (int mi = 0; mi < 2; mi++) af[mi]  = *(const bf16x8*)&As[buf][wr + mi*16 + lr][lk*8];
    #pragma unroll
    for (int ni = 0; ni < 2; ni++) bf_[ni] = *(const bf16x8*)&Bs[buf][wc + ni*16 + lr][lk*8];
    #pragma unroll
    for (int mi = 0; mi < 2; mi++)
      #pragma unroll
      for (int ni = 0; ni < 2; ni++)
        acc[mi][ni] = __builtin_amdgcn_mfma_f32_16x16x32_bf16(af[mi], bf_[ni], acc[mi][ni], 0, 0, 0);
  };

  int nst = Kd >> 5;                    // even
  LOADS(0);
  STOREK(0);
  LOADS(32);
  __syncthreads();
  for (int s = 0; s < nst; s += 2){
    COMPUTE(0);
    STOREK(1);
    if (s + 2 < nst) LOADS((s + 2) * 32);
    __syncthreads();
    COMPUTE(1);
    if (s + 2 < nst){
      STOREK(0);
      if (s + 3 < nst) LOADS((s + 3) * 32);
      __syncthreads();
    }
  }

  #pragma unroll
  for (int mi = 0; mi < 2; mi++){
    #pragma unroll
    for (int ni = 0; ni < 2; ni++){
      int col = nb + wc + ni*16 + lr;
      float bs = bias[col];
      #pragma unroll
      for (int r = 0; r < 4; r++){
        int row = rb + wr + mi*16 + lk*4 + r;
        if (row < rows){
          float v = acc[mi][ni][r] + bs;
          if (RES) v += Rres[(size_t)row*Nc + col];
          if (ACT == 1) v = 0.5f*v*(1.0f + erff(v*0.70710678118654752f));
          if constexpr (std::is_same<CT, float>::value) C[(size_t)row*Nc + col] = v;
          else C[(size_t)row*Nc + col] = __float2bfloat16(v);
        }
      }
    }
  }
}

// ==================== row LayerNorm (D=512), optional residual + relu. NO restrict (may run in place). ====================
template<typename XT, typename OT>
__global__ __launch_bounds__(256) void k_ln(const XT* X, const float* R,
                                            const float* g, const float* bt,
                                            OT* out, int relu)
{
  __shared__ float red[4];
  int row = blockIdx.x, t = threadIdx.x;
  size_t base = (size_t)row * 512;
  float x0, x1;
  if constexpr (std::is_same<XT, float>::value){ x0 = X[base + t]; x1 = X[base + t + 256]; }
  else { x0 = b2f(X[base + t]); x1 = b2f(X[base + t + 256]); }
  if (R){ x0 += R[base + t]; x1 += R[base + t + 256]; }
  float v = x0 + x1;
  #pragma unroll
  for (int o = 32; o > 0; o >>= 1) v += __shfl_xor(v, o);
  if ((t & 63) == 0) red[t >> 6] = v;
  __syncthreads();
  float mean = (red[0]+red[1]+red[2]+red[3]) * (1.0f/512.0f);
  float d0 = x0 - mean, d1 = x1 - mean;
  v = d0*d0 + d1*d1;
  #pragma unroll
  for (int o = 32; o > 0; o >>= 1) v += __shfl_xor(v, o);
  __syncthreads();
  if ((t & 63) == 0) red[t >> 6] = v;
  __syncthreads();
  float var = (red[0]+red[1]+red[2]+red[3]) * (1.0f/512.0f);
  float is = 1.0f / sqrtf(var + 1e-5f);
  float y0 = d0*is*g[t] + bt[t];
  float y1 = d1*is*g[t+256] + bt[t+256];
  if (relu){ y0 = fmaxf(y0, 0.0f); y1 = fmaxf(y1, 0.0f); }
  if constexpr (std::is_same<OT, float>::value){ out[base + t] = y0; out[base + t + 256] = y1; }
  else { out[base + t] = __float2bfloat16(y0); out[base + t + 256] = __float2bfloat16(y1); }
}

// ==================== bev transpose [64, 512, 256] f32 -> [16384, 512] bf16 ====================
__global__ void k_bev_tok(const float* __restrict__ bev, bf16* __restrict__ out){
  __shared__ float tile[32][33];
  int b = blockIdx.z;
  int d0 = blockIdx.x * 32;
  int p0 = blockIdx.y * 32;
  int tx = threadIdx.x, ty = threadIdx.y;
  #pragma unroll
  for (int i = 0; i < 4; i++){
    int d = d0 + ty + i*8;
    tile[ty + i*8][tx] = bev[((size_t)b*512 + d)*256 + p0 + tx];
  }
  __syncthreads();
  #pragma unroll
  for (int i = 0; i < 4; i++){
    int p = p0 + ty + i*8;
    out[((size_t)b*256 + p)*512 + d0 + tx] = __float2bfloat16(tile[tx][ty + i*8]);
  }
}

// ==================== top-K agents + invalid mask ====================
__global__ void k_topk(const float* __restrict__ labels, const float* __restrict__ states,
                       int* __restrict__ idxo, int* __restrict__ invo)
{
  __shared__ float dist[32];
  __shared__ int valid[32];
  int b = blockIdx.x, t = threadIdx.x;
  if (t < 32){
    float lab = labels[b*32 + t];
    float sg = 1.0f / (1.0f + expf(-lab));
    int va = sg > 0.05f;
    float x = states[((size_t)b*32 + t)*8 + 0];
    float y = states[((size_t)b*32 + t)*8 + 1];
    float d = sqrtf(__fadd_rn(__fmul_rn(x,x), __fmul_rn(y,y)));
    dist[t] = va ? d : INFINITY;
    valid[t] = va;
  }
  __syncthreads();
  if (t == 0){
    unsigned used = 0;
    int inv8[8]; int allinv = 1;
    for (int kk = 0; kk < 8; kk++){
      float best = INFINITY; int bi = -1;
      for (int i = 0; i < 32; i++){
        if (used & (1u << i)) continue;
        if (bi < 0 || dist[i] < best){ best = dist[i]; bi = i; }
      }
      used |= 1u << bi;
      idxo[b*8 + kk] = bi;
      inv8[kk] = !valid[bi];
      allinv &= inv8[kk];
    }
    for (int kk = 0; kk < 8; kk++) invo[b*8 + kk] = allinv ? 0 : inv8[kk];
  }
}

// ==================== gather agents f32 -> bf16 [512,512] ====================
__global__ void k_gather(const float* __restrict__ aq, const int* __restrict__ idx, bf16* __restrict__ out)
{
  int rk = blockIdx.x; int b = rk >> 3;
  int src = idx[rk] & 31;
  int t = threadIdx.x;
  size_t sbase = ((size_t)(b*32 + src))*512;
  out[(size_t)rk*512 + t]       = __float2bfloat16(aq[sbase + t]);
  out[(size_t)rk*512 + t + 256] = __float2bfloat16(aq[sbase + t + 256]);
}

// ==================== agent_kv f32 enc -> bf16 [4096,512] ====================
__global__ void k_agentkv(const float* __restrict__ enc, const float* __restrict__ step_e,
                          const float* __restrict__ role_e, bf16* __restrict__ out)
{
  int row = blockIdx.x;
  int t8 = row & 7; int bk = row >> 3;
  int tx = threadIdx.x;
  #pragma unroll
  for (int j = 0; j < 2; j++){
    int d = tx + j*256;
    out[(size_t)row*512 + d] = __float2bfloat16((enc[(size_t)bk*512 + d] + step_e[t8*512 + d]) + role_e[512 + d]);
  }
}

// ==================== sequential codebook NN scan -> tokens [B,T] ====================
__global__ __launch_bounds__(64) void k_cbscan(const float* __restrict__ gt, const float* __restrict__ cb,
                                               int* __restrict__ toks)
{
  __shared__ float cbx[512], cby[512];
  int b = blockIdx.x;
  int l = threadIdx.x;
  #pragma unroll
  for (int i = 0; i < 8; i++){
    int v = l + i*64;
    cbx[v] = cb[v*2 + 0];
    cby[v] = cb[v*2 + 1];
  }
  __syncthreads();
  float ax = 0.0f, ay = 0.0f;
  for (int t = 0; t < 8; t++){
    float px = gt[(b*8 + t)*3 + 0];
    float py = gt[(b*8 + t)*3 + 1];
    float bestv = INFINITY; int besti = 0;
    #pragma unroll
    for (int i = 0; i < 8; i++){
      int v = l*8 + i;
      float dx = __fsub_rn(__fadd_rn(ax, cbx[v]), px);
      float dy = __fsub_rn(__fadd_rn(ay, cby[v]), py);
      float d = __fadd_rn(__fmul_rn(dx,dx), __fmul_rn(dy,dy));
      if (d < bestv || (d == bestv && v < besti)){ bestv = d; besti = v; }
    }
    #pragma unroll
    for (int o = 32; o > 0; o >>= 1){
      float ov = __shfl_xor(bestv, o);
      int oi = __shfl_xor(besti, o);
      if (ov < bestv || (ov == bestv && oi < besti)){ bestv = ov; besti = oi; }
    }
    ax = __fadd_rn(ax, cbx[besti]);
    ay = __fadd_rn(ay, cby[besti]);
    if (l == 0) toks[b*8 + t] = besti;
  }
}

// ==================== teacher-forced embedding -> egoq f32 ====================
__global__ void k_embed(const int* __restrict__ toks, const float* __restrict__ ebase,
                        const float* __restrict__ tok_emb, const float* __restrict__ step_e,
                        const float* __restrict__ mode_e, const float* __restrict__ role_e,
                        const float* __restrict__ bos_e, float* __restrict__ out)
{
  int row = blockIdx.x;
  int t = row & 7; int bm = row >> 3; int m = bm % 20; int b = bm / 20;
  int tok = (t == 0) ? 0 : (toks[b*8 + t - 1] & 511);
  int tx = threadIdx.x;
  #pragma unroll
  for (int j = 0; j < 2; j++){
    int d = tx + j*256;
    float base = (t == 0) ? (bos_e[d] + ebase[(size_t)b*512 + d])
                          : tok_emb[(size_t)tok*512 + d];
    out[(size_t)row*512 + d] = ((base + step_e[t*512 + d]) + role_e[d]) + mode_e[m*512 + d];
  }
}

// ==================== temporal causal attention (QKV bf16 [rows,1536] -> O bf16) ====================
__global__ __launch_bounds__(64) void k_tattn(const bf16* __restrict__ QKV, bf16* __restrict__ O)
{
  __shared__ float q[8][65], k[8][65], v[8][65], w[8][9];
  int h = blockIdx.x & 7; int bm = blockIdx.x >> 3;
  int l = threadIdx.x;
  for (int t = 0; t < 8; t++){
    size_t base = ((size_t)(bm*8 + t))*1536 + h*64 + l;
    q[t][l] = b2f(QKV[base]);
    k[t][l] = b2f(QKV[base + 512]);
    v[t][l] = b2f(QKV[base + 1024]);
  }
  __syncthreads();
  int tq = l >> 3, tk = l & 7;
  float s = -INFINITY;
  if (tk <= tq){
    float acc = 0.0f;
    #pragma unroll
    for (int e = 0; e < 64; e++) acc += q[tq][e]*k[tk][e];
    s = acc * 0.125f;
  }
  float mx = s;
  #pragma unroll
  for (int o = 1; o < 8; o <<= 1) mx = fmaxf(mx, __shfl_xor(mx, o));
  float ex = (tk <= tq) ? expf(s - mx) : 0.0f;
  float sm = ex;
  #pragma unroll
  for (int o = 1; o < 8; o <<= 1) sm += __shfl_xor(sm, o);
  w[tq][tk] = ex / sm;
  __syncthreads();
  #pragma unroll
  for (int t2 = 0; t2 < 8; t2++){
    float acc = 0.0f;
    #pragma unroll
    for (int tk2 = 0; tk2 < 8; tk2++) acc += w[t2][tk2]*v[tk2][l];
    O[((size_t)(bm*8 + t2))*512 + h*64 + l] = __float2bfloat16(acc);
  }
}

// ==================== ego-to-agent cross-attention; KV interleaved [4096,1024] (K|V) ====================
__global__ __launch_bounds__(64) void k_eattn(const bf16* __restrict__ Q, const bf16* __restrict__ KV,
                                              const int* __restrict__ inv,
                                              bf16* __restrict__ O, int row0)
{
  int blk = blockIdx.x;
  int h = blockIdx.y;
  int grow = row0 + blk;
  int t = grow & 7;
  int b = grow / 160;
  int l = threadIdx.x;
  size_t qoff = (size_t)blk*512 + h*64 + l;
  float q = b2f(Q[qoff]);
  float s[8];
  #pragma unroll
  for (int k = 0; k < 8; k++){
    float p = q * b2f(KV[((size_t)((b*8 + k)*8 + t))*1024 + h*64 + l]);
    #pragma unroll
    for (int o = 32; o > 0; o >>= 1) p += __shfl_xor(p, o);
    s[k] = p * 0.125f;
  }
  float mx = -INFINITY;
  #pragma unroll
  for (int k = 0; k < 8; k++){
    if (inv[b*8 + k]) s[k] = -INFINITY;
    mx = fmaxf(mx, s[k]);
  }
  float sum = 0.0f, w[8];
  #pragma unroll
  for (int k = 0; k < 8; k++){ w[k] = expf(s[k] - mx); sum += w[k]; }
  float rs = 1.0f / sum;
  float acc = 0.0f;
  #pragma unroll
  for (int k = 0; k < 8; k++)
    acc += (w[k]*rs) * b2f(KV[((size_t)((b*8 + k)*8 + t))*1024 + 512 + h*64 + l]);
  O[qoff] = __float2bfloat16(acc);
}

// ==================== BEV cross-attention v5 (MFMA flash-style); bl spans grid.x ====================
__global__ __launch_bounds__(256, 2) void k_vattn(const bf16* __restrict__ Q, const bf16* __restrict__ KV,
                                                  bf16* __restrict__ O)
{
  __shared__ unsigned short Ks[256][72];   // P [32][264] aliases this after scores
  __shared__ unsigned short Vt[64][264];   // V transposed [e][key]
  __shared__ float red[2][2][16];
  unsigned short (*P_lds)[264] = (unsigned short (*)[264])&Ks[0][0];

  int bl = blockIdx.x, h = blockIdx.y, qz = blockIdx.z;
  int tid = threadIdx.x;
  const unsigned short* KVr = (const unsigned short*)KV;

  {
    const uint4* ksrc = (const uint4*)&KVr[((size_t)(bl*256 + tid))*1024 + h*64];
    const uint4* vsrc = (const uint4*)&KVr[((size_t)(bl*256 + tid))*1024 + 512 + h*64];
    #pragma unroll
    for (int i = 0; i < 8; i++){
      uint4 kx = ksrc[i];
      *(uint4*)&Ks[tid][i*8] = kx;
    }
    #pragma unroll
    for (int i = 0; i < 8; i++){
      uint4 vx = vsrc[i];
      unsigned short vs[8];
      __builtin_memcpy(vs, &vx, 16);
      #pragma unroll
      for (int j = 0; j < 8; j++) Vt[i*8 + j][tid] = vs[j];
    }
  }
  __syncthreads();

  int w = tid >> 6, l = tid & 63, lr = l & 15, lk = l >> 4;
  int mt = w >> 1, ch = w & 1;

  int qrow = bl*160 + qz*32 + mt*16 + lr;
  const unsigned short* Qr = (const unsigned short*)Q;
  bf16x8 qf0 = *(const bf16x8*)&Qr[(size_t)qrow*512 + h*64 + lk*8];
  bf16x8 qf1 = *(const bf16x8*)&Qr[(size_t)qrow*512 + h*64 + 32 + lk*8];

  f32x4 sacc[8];
  #pragma unroll
  for (int nt = 0; nt < 8; nt++) sacc[nt] = (f32x4){0.f,0.f,0.f,0.f};
  #pragma unroll
  for (int nt = 0; nt < 8; nt++){
    int key0 = ch*128 + nt*16 + lr;
    bf16x8 kf0 = *(const bf16x8*)&Ks[key0][lk*8];
    bf16x8 kf1 = *(const bf16x8*)&Ks[key0][32 + lk*8];
    sacc[nt] = __builtin_amdgcn_mfma_f32_16x16x32_bf16(qf0, kf0, sacc[nt], 0, 0, 0);
    sacc[nt] = __builtin_amdgcn_mfma_f32_16x16x32_bf16(qf1, kf1, sacc[nt], 0, 0, 0);
  }

  float rmax[4] = {-INFINITY, -INFINITY, -INFINITY, -INFINITY};
  #pragma unroll
  for (int nt = 0; nt < 8; nt++)
    #pragma unroll
    for (int r = 0; r < 4; r++){
      float v = sacc[nt][r] * 0.125f;
      sacc[nt][r] = v;
      rmax[r] = fmaxf(rmax[r], v);
    }
  #pragma unroll
  for (int r = 0; r < 4; r++){
    #pragma unroll
    for (int o = 1; o < 16; o <<= 1) rmax[r] = fmaxf(rmax[r], __shfl_xor(rmax[r], o));
  }
  if (lr == 0){
    #pragma unroll
    for (int r = 0; r < 4; r++) red[mt][ch][lk*4 + r] = rmax[r];
  }
  __syncthreads();
  float m4[4];
  #pragma unroll
  for (int r = 0; r < 4; r++) m4[r] = fmaxf(red[mt][0][lk*4 + r], red[mt][1][lk*4 + r]);
  float rsum[4] = {0.f, 0.f, 0.f, 0.f};
  #pragma unroll
  for (int nt = 0; nt < 8; nt++){
    #pragma unroll
    for (int r = 0; r < 4; r++){
      float e = expf(sacc[nt][r] - m4[r]);
      rsum[r] += e;
      P_lds[mt*16 + lk*4 + r][ch*128 + nt*16 + lr] = (unsigned short)f2s(e);
    }
  }
  #pragma unroll
  for (int r = 0; r < 4; r++){
    #pragma unroll
    for (int o = 1; o < 16; o <<= 1) rsum[r] += __shfl_xor(rsum[r], o);
  }
  __syncthreads();
  if (lr == 0){
    #pragma unroll
    for (int r = 0; r < 4; r++) red[mt][ch][lk*4 + r] = rsum[r];
  }
  __syncthreads();
  float rcp4[4];
  #pragma unroll
  for (int r = 0; r < 4; r++) rcp4[r] = 1.0f / (red[mt][0][lk*4 + r] + red[mt][1][lk*4 + r]);

  f32x4 oacc0 = (f32x4){0.f,0.f,0.f,0.f};
  f32x4 oacc1 = (f32x4){0.f,0.f,0.f,0.f};
  #pragma unroll
  for (int kk = 0; kk < 8; kk++){
    bf16x8 pf  = *(const bf16x8*)&P_lds[mt*16 + lr][kk*32 + lk*8];
    bf16x8 vf0 = *(const bf16x8*)&Vt[ch*32 + lr][kk*32 + lk*8];
    bf16x8 vf1 = *(const bf16x8*)&Vt[ch*32 + 16 + lr][kk*32 + lk*8];
    oacc0 = __builtin_amdgcn_mfma_f32_16x16x32_bf16(pf, vf0, oacc0, 0, 0, 0);
    oacc1 = __builtin_amdgcn_mfma_f32_16x16x32_bf16(pf, vf1, oacc1, 0, 0, 0);
  }

  {
    size_t obase = ((size_t)(bl*160 + qz*32 + mt*16 + lk*4))*512 + h*64 + ch*32 + lr;
    #pragma unroll
    for (int r = 0; r < 4; r++){
      O[obase + (size_t)r*512]      = __float2bfloat16(oacc0[r] * rcp4[r]);
      O[obase + (size_t)r*512 + 16] = __float2bfloat16(oacc1[r] * rcp4[r]);
    }
  }
}

// ==================== launchers ====================
template<typename AT, typename CT, int ACT, int BN, int RES>
static inline void launch_gemm(bool wbf, const AT* A, const float* Wf, const bf16* Wb,
                               const float* bias, CT* C, const float* Rr,
                               int rows, int Kd, int Nc, hipStream_t st){
  dim3 g((rows + 127)/128, Nc/BN);
  if (wbf) k_gemm_mfma<AT,bf16,CT,ACT,BN,RES><<<g,256,0,st>>>(A, Wb, bias, C, Rr, rows, Kd, Nc);
  else     k_gemm_mfma<AT,float,CT,ACT,BN,RES><<<g,256,0,st>>>(A, Wf, bias, C, Rr, rows, Kd, Nc);
}
template<typename AT, typename CT, int ACT, int RES>
static inline void launch_gemm64(bool wbf, const AT* A, const float* Wf, const bf16* Wb,
                                 const float* bias, CT* C, const float* Rr,
                                 int rows, int Kd, int Nc, hipStream_t st){
  dim3 g((rows + 63)/64, Nc/64);
  if (wbf) k_gemm64<AT,bf16,CT,ACT,RES><<<g,256,0,st>>>(A, Wb, bias, C, Rr, rows, Kd, Nc);
  else     k_gemm64<AT,float,CT,ACT,RES><<<g,256,0,st>>>(A, Wf, bias, C, Rr, rows, Kd, Nc);
}

extern "C" void kernel_launch(void* const* d_in, const int* in_sizes, int n_in,
                              void* d_out, int out_size, void* d_ws, size_t ws_size,
                              hipStream_t stream)
{
  (void)in_sizes; (void)n_in; (void)out_size;
  const float* ego_query    = (const float*)d_in[0];
  const float* agents_query = (const float*)d_in[1];
  const float* bev_feature  = (const float*)d_in[2];
  const float* agent_states = (const float*)d_in[3];
  const float* agent_labels = (const float*)d_in[4];
  const float* gt_traj      = (const float*)d_in[5];
  const float* codebook     = (const float*)d_in[6];
  const float* ego_ctx_w    = (const float*)d_in[7];
  const float* ego_ctx_b    = (const float*)d_in[8];
  const float* ego_ctx_g    = (const float*)d_in[9];
  const float* ego_ctx_beta = (const float*)d_in[10];
  const float* bevproj_w    = (const float*)d_in[11];
  const float* bevproj_b    = (const float*)d_in[12];
  const float* bevproj_g    = (const float*)d_in[13];
  const float* bevproj_beta = (const float*)d_in[14];
  const float* agent_w      = (const float*)d_in[15];
  const float* agent_b      = (const float*)d_in[16];
  const float* agent_g      = (const float*)d_in[17];
  const float* agent_beta   = (const float*)d_in[18];
  const float* tok_emb      = (const float*)d_in[19];
  const float* step_e       = (const float*)d_in[20];
  const float* mode_e       = (const float*)d_in[21];
  const float* role_e       = (const float*)d_in[22];
  const float* bos_e        = (const float*)d_in[23];
  const float* t_qkv_w      = (const float*)d_in[24];
  const float* t_qkv_b      = (const float*)d_in[25];
  const float* t_out_w      = (const float*)d_in[26];
  const float* t_out_b      = (const float*)d_in[27];
  const float* t_g          = (const float*)d_in[28];
  const float* t_beta       = (const float*)d_in[29];
  const float* e_qkv_w      = (const float*)d_in[30];
  const float* e_qkv_b      = (const float*)d_in[31];
  const float* e_out_w      = (const float*)d_in[32];
  const float* e_out_b      = (const float*)d_in[33];
  const float* e_g          = (const float*)d_in[34];
  const float* e_beta       = (const float*)d_in[35];
  const float* v_qkv_w      = (const float*)d_in[36];
  const float* v_qkv_b      = (const float*)d_in[37];
  const float* v_out_w      = (const float*)d_in[38];
  const float* v_out_b      = (const float*)d_in[39];
  const float* v_g          = (const float*)d_in[40];
  const float* v_beta       = (const float*)d_in[41];
  const float* ffn_w1       = (const float*)d_in[42];
  const float* ffn_b1       = (const float*)d_in[43];
  const float* ffn_w2       = (const float*)d_in[44];
  const float* ffn_b2       = (const float*)d_in[45];
  const float* ffn_g        = (const float*)d_in[46];
  const float* ffn_beta     = (const float*)d_in[47];
  const float* head_w       = (const float*)d_in[48];
  const float* head_b       = (const float*)d_in[49];

  // ---- workspace tiers: small 46.3 / big 67.3 / big2 100.8 / big3 123.9 MB (bf16 weights) ----
  const size_t NEEDED       = 46274560;
  const size_t NEEDED_BIG   = 67248128;
  const size_t NEEDED_BIG2  = 100800512;
  const size_t NEEDED_BIG3  = 123869184;
  if (ws_size < NEEDED) return;
  bool big  = ws_size >= NEEDED_BIG;
  bool big2 = ws_size >= NEEDED_BIG2;
  bool big3 = ws_size >= NEEDED_BIG3;
  int RC  = big ? 10240 : 5120;
  int NCH = big ? 1 : 2;

  char* WB = (char*)d_ws;
  bf16*  bevtok = (bf16*)(WB + 0);          // [16384,512] bf16 persistent
  bf16*  akv    = (bf16*)(WB + 16777216);   // [4096,512] bf16 persistent
  float* ebase  = (float*)(WB + 20971520);  // [64,512] f32
  char*  ARENA  = WB + 21102592;
  bf16*  KVb    = (bf16*)(WB + 37879808);   // [4096,1024] bf16
  bf16*  KVbig  = (bf16*)(WB + 67239936);   // [16384,1024] bf16 (big2+)
  bf16*  WCV    = (bf16*)(WB + 100800512);  // [11,534,336] bf16 converted weights (big3)
  size_t tk0    = big2 ? 100794368 : (big ? 67239936 : 46268416);
  int*   toks   = (int*)(WB + tk0);
  int*   idxb   = (int*)(WB + tk0 + 2048);
  int*   invb   = (int*)(WB + tk0 + 4096);
  size_t oe_off = big ? 31457280 : 5242880;

  float* egoq = (float*)d_out;   // [10240,512] f32 residual stream lives in d_out

  // converted-weight element offsets
  bf16* c_bevproj = WCV + 0;
  bf16* c_ego     = WCV + 262144;
  bf16* c_agent   = WCV + 524288;
  bf16* c_tqkv    = WCV + 786432;
  bf16* c_tout    = WCV + 2359296;
  bf16* c_eqkv    = WCV + 2883584;
  bf16* c_eout    = WCV + 4456448;
  bf16* c_vqkv    = WCV + 4980736;
  bf16* c_vout    = WCV + 6553600;
  bf16* c_ffn1    = WCV + 7077888;
  bf16* c_ffn2    = WCV + 9175040;
  bf16* c_head    = WCV + 11272192;

  if (big3){
    WSrc src;
    src.p[0] = bevproj_w; src.p[1] = ego_ctx_w; src.p[2] = agent_w;  src.p[3] = t_qkv_w;
    src.p[4] = t_out_w;   src.p[5] = e_qkv_w;   src.p[6] = e_out_w;  src.p[7] = v_qkv_w;
    src.p[8] = v_out_w;   src.p[9] = ffn_w1;    src.p[10] = ffn_w2;  src.p[11] = head_w;
    k_cvtw<<<5632, 256, 0, stream>>>(src, WCV);
  }

  #define GEMM(AT,CT,ACT,BN,RES, Ap, Wf, Wb, Bp,Cp,Rp, R,K,N) \
    launch_gemm<AT,CT,ACT,BN,RES>(big3, Ap, Wf, Wb, Bp, Cp, Rp, R, K, N, stream)
  #define GEMM64(AT,CT,ACT,RES, Ap, Wf, Wb, Bp,Cp,Rp, R,K,N) \
    launch_gemm64<AT,CT,ACT,RES>(big3, Ap, Wf, Wb, Bp, Cp, Rp, R, K, N, stream)

  // --- BEV tokens ONCE ---
  {
    bf16* raw = (bf16*)ARENA;   // [16384,512]
    k_bev_tok<<<dim3(16, 8, 64), dim3(32, 8), 0, stream>>>(bev_feature, raw);
    GEMM64(bf16,bf16,0,0, raw, bevproj_w, c_bevproj, bevproj_b, bevtok, nullptr, 16384, 512, 512);
    k_ln<bf16,bf16><<<16384, 256, 0, stream>>>(bevtok, nullptr, bevproj_g, bevproj_beta, bevtok, 1);
  }

  // --- ego base ---
  GEMM64(float,float,0,0, ego_query, ego_ctx_w, c_ego, ego_ctx_b, (float*)ARENA, nullptr, 64, 512, 512);
  k_ln<float,float><<<64, 256, 0, stream>>>((float*)ARENA, nullptr, ego_ctx_g, ego_ctx_beta, ebase, 1);

  // --- agents ---
  k_topk<<<64, 64, 0, stream>>>(agent_labels, agent_states, idxb, invb);
  {
    bf16*  gat = (bf16*)ARENA;                   // [512,512] bf16
    float* enc = (float*)(ARENA + 524288);       // [512,512] f32
    k_gather<<<512, 256, 0, stream>>>(agents_query, idxb, gat);
    GEMM64(bf16,float,0,0, gat, agent_w, c_agent, agent_b, enc, nullptr, 512, 512, 512);
    k_ln<float,float><<<512, 256, 0, stream>>>(enc, nullptr, agent_g, agent_beta, enc, 1);
    k_agentkv<<<4096, 256, 0, stream>>>(enc, step_e, role_e, akv);
  }

  // --- tokens + embedding ---
  k_cbscan<<<64, 64, 0, stream>>>(gt_traj, codebook, toks);
  k_embed<<<10240, 256, 0, stream>>>(toks, ebase, tok_emb, step_e, mode_e, role_e, bos_e, egoq);

  for (int i = 0; i < 2; i++){
    // ---- temporal self-attention ----
    {
      bf16* QKV = (bf16*)ARENA;                 // [RC,1536]
      bf16* Ot  = big ? (bf16*)(ARENA + oe_off) : KVb;   // [RC,512]
      for (int c = 0; c < NCH; c++){
        float* eg = egoq + (size_t)c*RC*512;
        GEMM(float,bf16,0,128,0, eg, t_qkv_w + (size_t)i*786432, c_tqkv + (size_t)i*786432,
             t_qkv_b + i*1536, QKV, nullptr, RC, 512, 1536);
        k_tattn<<<RC, 64, 0, stream>>>(QKV, Ot);
        GEMM64(bf16,float,0,1, Ot, t_out_w + (size_t)i*262144, c_tout + (size_t)i*262144,
             t_out_b + i*512, eg, eg, RC, 512, 512);
      }
      k_ln<float,float><<<10240, 256, 0, stream>>>(egoq, nullptr, t_g + i*512, t_beta + i*512, egoq, 0);
    }
    // ---- ego-to-agent cross-attention ----
    {
      const float* eqw = e_qkv_w + (size_t)i*786432;
      bf16*        eqc = c_eqkv + (size_t)i*786432;
      const float* eqb = e_qkv_b + i*1536;
      bf16* Qe = (bf16*)ARENA;                  // [RC,512]
      bf16* Oe = (bf16*)(ARENA + oe_off);       // [RC,512]
      GEMM64(bf16,bf16,0,0, akv, eqw + 262144, eqc + 262144, eqb + 512, KVb, nullptr, 4096, 512, 1024);
      for (int c = 0; c < NCH; c++){
        float* eg = egoq + (size_t)c*RC*512;
        GEMM64(float,bf16,0,0, eg, eqw, eqc, eqb, Qe, nullptr, RC, 512, 512);
        k_eattn<<<dim3(RC, 8), 64, 0, stream>>>(Qe, KVb, invb, Oe, c*RC);
        GEMM64(bf16,float,0,1, Oe, e_out_w + (size_t)i*262144, c_eout + (size_t)i*262144,
             e_out_b + i*512, eg, eg, RC, 512, 512);
      }
      k_ln<float,float><<<10240, 256, 0, stream>>>(egoq, nullptr, e_g + i*512, e_beta + i*512, egoq, 0);
    }
    // ---- BEV cross-attention ----
    {
      const float* vqw = v_qkv_w + (size_t)i*786432;
      bf16*        vqc = c_vqkv + (size_t)i*786432;
      const float* vqb = v_qkv_b + i*1536;
      if (big2){
        bf16* Qv = (bf16*)ARENA;                  // [10240,512]
        bf16* Ov = (bf16*)(ARENA + 10485760);     // [10240,512]
        GEMM64(bf16,bf16,0,0, bevtok, vqw + 262144, vqc + 262144, vqb + 512, KVbig, nullptr, 16384, 512, 1024);
        GEMM64(float,bf16,0,0, egoq, vqw, vqc, vqb, Qv, nullptr, 10240, 512, 512);
        k_vattn<<<dim3(64, 8, 5), 256, 0, stream>>>(Qv, KVbig, Ov);
        GEMM64(bf16,float,0,1, Ov, v_out_w + (size_t)i*262144, c_vout + (size_t)i*262144,
             v_out_b + i*512, egoq, egoq, 10240, 512, 512);
      } else {
        bf16* Qv = (bf16*)ARENA;                  // [2560,512]
        bf16* Ov = (bf16*)(ARENA + 2621440);      // [2560,512]
        for (int gidx = 0; gidx < 4; gidx++){
          float* eg = egoq + (size_t)gidx*2560*512;
          GEMM64(bf16,bf16,0,0, bevtok + (size_t)gidx*4096*512, vqw + 262144, vqc + 262144,
               vqb + 512, KVb, nullptr, 4096, 512, 1024);
          GEMM64(float,bf16,0,0, eg, vqw, vqc, vqb, Qv, nullptr, 2560, 512, 512);
          k_vattn<<<dim3(16, 8, 5), 256, 0, stream>>>(Qv, KVb, Ov);
          GEMM64(bf16,float,0,1, Ov, v_out_w + (size_t)i*262144, c_vout + (size_t)i*262144,
               v_out_b + i*512, eg, eg, 2560, 512, 512);
        }
      }
      k_ln<float,float><<<10240, 256, 0, stream>>>(egoq, nullptr, v_g + i*512, v_beta + i*512, egoq, 0);
    }
    // ---- FFN ----
    {
      bf16* hid = (bf16*)ARENA;   // [RC,2048]
      for (int c = 0; c < NCH; c++){
        float* eg = egoq + (size_t)c*RC*512;
        GEMM(float,bf16,1,128,0, eg, ffn_w1 + (size_t)i*1048576, c_ffn1 + (size_t)i*1048576,
             ffn_b1 + i*2048, hid, nullptr, RC, 512, 2048);
        GEMM64(bf16,float,0,1, hid, ffn_w2 + (size_t)i*1048576, c_ffn2 + (size_t)i*1048576,
             ffn_b2 + i*512, eg, eg, RC, 2048, 512);
      }
      if (i == 0){
        k_ln<float,float><<<10240, 256, 0, stream>>>(egoq, nullptr, ffn_g, ffn_beta, egoq, 0);
      } else {
        k_ln<float,bf16><<<10240, 256, 0, stream>>>(egoq, nullptr, ffn_g + 512, ffn_beta + 512, (bf16*)ARENA, 0);
      }
    }
  }

  // --- head ---
  GEMM64(bf16,float,0,0, (bf16*)ARENA, head_w, c_head, head_b, (float*)d_out, nullptr, 10240, 512, 512);
  #undef GEMM
  #undef GEMM64
}